// Round 1
// baseline (733.327 us; speedup 1.0000x reference)
//
#include <hip/hip_runtime.h>
#include <cstddef>

// ReBased linear attention, fp32 baseline.
// B=2, L=2048, HID=1024, H=16, FD=16, HD=64.
// Pipeline:
//   qk_raw[4096][512] = x @ [Wq;Wk]^T        (gemm_nt, dual-W)
//   vbuf  [4096][1024] = x @ Wv^T            (gemm_nt)
//   ln_featuremap: in-place LN per 16-elem group on qk_raw (+q scale 0.25)
//   rebased_attn: causal (q.k)^2 attention -> obuf[4096][1024] (b,l,h*64+d)
//   out[4096][1024] = obuf @ Wo^T            (gemm_nt)

#define GTM 128
#define GTN 128
#define GTK 32

// C[M][N] = A[M][K] @ W^T, where W row n = (n < nsplit ? W1[n] : W2[n-nsplit]).
__global__ __launch_bounds__(256) void gemm_nt(const float* __restrict__ A,
                                               const float* __restrict__ W1,
                                               const float* __restrict__ W2,
                                               float* __restrict__ C,
                                               int M, int N, int K, int nsplit) {
    __shared__ __align__(16) float As[GTK][132];
    __shared__ __align__(16) float Ws[GTK][132];
    const int t  = threadIdx.x;
    const int m0 = blockIdx.x * GTM;
    const int n0 = blockIdx.y * GTN;
    const float* Wp = (n0 < nsplit) ? W1 : W2;
    const int nb    = (n0 < nsplit) ? n0 : (n0 - nsplit);
    const int tr4 = (t >> 4) << 2;   // 0..60 step 4
    const int tc4 = (t & 15) << 2;   // 0..60 step 4

    float acc[2][2][4][4];
#pragma unroll
    for (int ra = 0; ra < 2; ++ra)
#pragma unroll
    for (int cb = 0; cb < 2; ++cb)
#pragma unroll
    for (int i = 0; i < 4; ++i)
#pragma unroll
    for (int j = 0; j < 4; ++j) acc[ra][cb][i][j] = 0.f;

    const int lc  = t & 31;          // k offset within tile
    const int lr0 = (t >> 5) << 2;   // 0,4,...,28

    for (int k0 = 0; k0 < K; k0 += GTK) {
        __syncthreads();
#pragma unroll
        for (int rep = 0; rep < 4; ++rep) {
            const int r4 = lr0 + (rep << 5);   // 0..124 step 4
            const size_t ak = (size_t)k0 + lc;
            float a0 = A[(size_t)(m0 + r4 + 0) * K + ak];
            float a1 = A[(size_t)(m0 + r4 + 1) * K + ak];
            float a2 = A[(size_t)(m0 + r4 + 2) * K + ak];
            float a3 = A[(size_t)(m0 + r4 + 3) * K + ak];
            *(float4*)&As[lc][r4] = make_float4(a0, a1, a2, a3);
            float w0 = Wp[(size_t)(nb + r4 + 0) * K + ak];
            float w1 = Wp[(size_t)(nb + r4 + 1) * K + ak];
            float w2 = Wp[(size_t)(nb + r4 + 2) * K + ak];
            float w3 = Wp[(size_t)(nb + r4 + 3) * K + ak];
            *(float4*)&Ws[lc][r4] = make_float4(w0, w1, w2, w3);
        }
        __syncthreads();
#pragma unroll 8
        for (int kk = 0; kk < GTK; ++kk) {
            float4 a0 = *(const float4*)&As[kk][tr4];
            float4 a1 = *(const float4*)&As[kk][64 + tr4];
            float4 b0 = *(const float4*)&Ws[kk][tc4];
            float4 b1 = *(const float4*)&Ws[kk][64 + tc4];
            float av[2][4] = {{a0.x, a0.y, a0.z, a0.w}, {a1.x, a1.y, a1.z, a1.w}};
            float bv[2][4] = {{b0.x, b0.y, b0.z, b0.w}, {b1.x, b1.y, b1.z, b1.w}};
#pragma unroll
            for (int ra = 0; ra < 2; ++ra)
#pragma unroll
            for (int cb = 0; cb < 2; ++cb)
#pragma unroll
            for (int i = 0; i < 4; ++i)
#pragma unroll
            for (int j = 0; j < 4; ++j)
                acc[ra][cb][i][j] = fmaf(av[ra][i], bv[cb][j], acc[ra][cb][i][j]);
        }
    }

#pragma unroll
    for (int ra = 0; ra < 2; ++ra)
#pragma unroll
    for (int i = 0; i < 4; ++i) {
        const int row = m0 + (ra << 6) + tr4 + i;
#pragma unroll
        for (int cb = 0; cb < 2; ++cb) {
            float4 v = make_float4(acc[ra][cb][i][0], acc[ra][cb][i][1],
                                   acc[ra][cb][i][2], acc[ra][cb][i][3]);
            *(float4*)&C[(size_t)row * N + n0 + (cb << 6) + tc4] = v;
        }
    }
}

// In-place feature map on qk_raw[4096][512]: groups of 16 contiguous floats.
// group g: m = g>>5, idx = g&31; idx<16 -> q head (scale 0.25), else k head.
__global__ __launch_bounds__(256) void ln_featuremap(float* __restrict__ qk,
                                                     const float* __restrict__ gamma,
                                                     const float* __restrict__ beta) {
    const int gid = blockIdx.x * 256 + threadIdx.x;   // 0..131071
    const int idx = gid & 31;
    float* p = qk + (size_t)gid * 16;
    const float scale = (idx < 16) ? 0.25f : 1.0f;

    float4 v0 = *(const float4*)(p + 0);
    float4 v1 = *(const float4*)(p + 4);
    float4 v2 = *(const float4*)(p + 8);
    float4 v3 = *(const float4*)(p + 12);
    float xv[16];
    xv[0]=v0.x; xv[1]=v0.y; xv[2]=v0.z; xv[3]=v0.w;
    xv[4]=v1.x; xv[5]=v1.y; xv[6]=v1.z; xv[7]=v1.w;
    xv[8]=v2.x; xv[9]=v2.y; xv[10]=v2.z; xv[11]=v2.w;
    xv[12]=v3.x; xv[13]=v3.y; xv[14]=v3.z; xv[15]=v3.w;

    float mu = 0.f;
#pragma unroll
    for (int f = 0; f < 16; ++f) mu += xv[f];
    mu *= 0.0625f;
    float var = 0.f;
#pragma unroll
    for (int f = 0; f < 16; ++f) { float d = xv[f] - mu; var = fmaf(d, d, var); }
    var *= 0.0625f;
    const float rs = rsqrtf(var + 1e-5f);
#pragma unroll
    for (int f = 0; f < 16; ++f)
        xv[f] = (fmaf(xv[f] - mu, rs, 0.f) * gamma[f] + beta[f]) * scale;

    *(float4*)(p + 0)  = make_float4(xv[0], xv[1], xv[2], xv[3]);
    *(float4*)(p + 4)  = make_float4(xv[4], xv[5], xv[6], xv[7]);
    *(float4*)(p + 8)  = make_float4(xv[8], xv[9], xv[10], xv[11]);
    *(float4*)(p + 12) = make_float4(xv[12], xv[13], xv[14], xv[15]);
}

// Causal (q.k)^2 attention with row-sum normalization.
// grid (16, 32): x = q-tile pair index, y = b*16+h. Each block does q-tiles
// {x, 31-x} (constant 33 key-tile steps -> balanced).
__global__ __launch_bounds__(256) void rebased_attn(const float* __restrict__ qk,
                                                    const float* __restrict__ v,
                                                    float* __restrict__ o) {
    const int bh = blockIdx.y;
    const int bb = bh >> 4, h = bh & 15;
    const int t = threadIdx.x;
    const int tr4 = (t >> 4) << 2;   // s/o row group
    const int tc4 = (t & 15) << 2;   // s col / o col group

    __shared__ __align__(16) float qT[16][68];
    __shared__ __align__(16) float kT[16][68];
    __shared__ __align__(16) float sT[64][68];
    __shared__ __align__(16) float vs[64][68];
    __shared__ float zp[64][17];
    __shared__ float zf[64];

    const float* qbh = qk + (size_t)bb * 2048 * 512 + h * 16;
    const float* kbh = qk + (size_t)bb * 2048 * 512 + 256 + h * 16;
    const float* vbh = v  + (size_t)bb * 2048 * 1024 + h * 64;
    float*       obh = o  + (size_t)bb * 2048 * 1024 + h * 64;

    const int ldj = t >> 2;            // 0..63 (loader row)
    const int lf4 = (t & 3) << 2;      // 0,4,8,12
    const int lc16 = (t & 3) << 4;     // 0,16,32,48

    for (int pass = 0; pass < 2; ++pass) {
        const int qt = pass ? (31 - (int)blockIdx.x) : (int)blockIdx.x;
        const int qbase = qt << 6;

        // load Q tile (transposed): qT[f][j] = q[qbase+j][f]
        {
            float4 qv = *(const float4*)&qbh[(size_t)(qbase + ldj) * 512 + lf4];
            qT[lf4 + 0][ldj] = qv.x; qT[lf4 + 1][ldj] = qv.y;
            qT[lf4 + 2][ldj] = qv.z; qT[lf4 + 3][ldj] = qv.w;
        }

        float oa[4][4];
        float zrow[4];
#pragma unroll
        for (int i = 0; i < 4; ++i) {
            zrow[i] = 0.f;
#pragma unroll
            for (int j = 0; j < 4; ++j) oa[i][j] = 0.f;
        }

        for (int kt = 0; kt <= qt; ++kt) {
            __syncthreads();   // prev phase-2 reads done (also covers qT store on kt=0)
            {
                float4 kv = *(const float4*)&kbh[(size_t)((kt << 6) + ldj) * 512 + lf4];
                kT[lf4 + 0][ldj] = kv.x; kT[lf4 + 1][ldj] = kv.y;
                kT[lf4 + 2][ldj] = kv.z; kT[lf4 + 3][ldj] = kv.w;
#pragma unroll
                for (int u = 0; u < 4; ++u) {
                    float4 vv = *(const float4*)&vbh[(size_t)((kt << 6) + ldj) * 1024 + lc16 + 4 * u];
                    *(float4*)&vs[ldj][lc16 + 4 * u] = vv;
                }
            }
            __syncthreads();

            // phase 1: s = (q.k)^2, causal mask, write sT, accumulate z
            float sa[4][4];
#pragma unroll
            for (int i = 0; i < 4; ++i)
#pragma unroll
            for (int j = 0; j < 4; ++j) sa[i][j] = 0.f;
#pragma unroll
            for (int f = 0; f < 16; ++f) {
                float4 a4 = *(const float4*)&qT[f][tr4];
                float4 b4 = *(const float4*)&kT[f][tc4];
                float av[4] = {a4.x, a4.y, a4.z, a4.w};
                float bv[4] = {b4.x, b4.y, b4.z, b4.w};
#pragma unroll
                for (int i = 0; i < 4; ++i)
#pragma unroll
                for (int j = 0; j < 4; ++j)
                    sa[i][j] = fmaf(av[i], bv[j], sa[i][j]);
            }
#pragma unroll
            for (int j = 0; j < 4; ++j) {
                const int col = (kt << 6) + tc4 + j;
                float sv[4];
#pragma unroll
                for (int i = 0; i < 4; ++i) {
                    const int row = qbase + tr4 + i;
                    const float d = sa[i][j];
                    const float s2 = (col <= row) ? d * d : 0.f;
                    sv[i] = s2;
                    zrow[i] += s2;
                }
                *(float4*)&sT[tc4 + j][tr4] = make_float4(sv[0], sv[1], sv[2], sv[3]);
            }
            __syncthreads();

            // phase 2: o += s @ v
#pragma unroll 4
            for (int j = 0; j < 64; ++j) {
                float4 a4 = *(const float4*)&sT[j][tr4];
                float4 b4 = *(const float4*)&vs[j][tc4];
                float av[4] = {a4.x, a4.y, a4.z, a4.w};
                float bv[4] = {b4.x, b4.y, b4.z, b4.w};
#pragma unroll
                for (int i = 0; i < 4; ++i)
#pragma unroll
                for (int cj = 0; cj < 4; ++cj)
                    oa[i][cj] = fmaf(av[i], bv[cj], oa[i][cj]);
            }
        }

        // z reduce + normalized write
        __syncthreads();
#pragma unroll
        for (int i = 0; i < 4; ++i) zp[tr4 + i][t & 15] = zrow[i];
        __syncthreads();
        if (t < 64) {
            float s = 1e-5f;
#pragma unroll
            for (int c = 0; c < 16; ++c) s += zp[t][c];
            zf[t] = 1.f / s;
        }
        __syncthreads();
#pragma unroll
        for (int i = 0; i < 4; ++i) {
            const float r = zf[tr4 + i];
            float4 ov = make_float4(oa[i][0] * r, oa[i][1] * r, oa[i][2] * r, oa[i][3] * r);
            *(float4*)&obh[(size_t)(qbase + tr4 + i) * 1024 + tc4] = ov;
        }
        __syncthreads();   // before next pass overwrites qT
    }
}

extern "C" void kernel_launch(void* const* d_in, const int* in_sizes, int n_in,
                              void* d_out, int out_size, void* d_ws, size_t ws_size,
                              hipStream_t stream) {
    const float* x     = (const float*)d_in[0];
    const float* Wq    = (const float*)d_in[1];
    const float* Wk    = (const float*)d_in[2];
    const float* Wv    = (const float*)d_in[3];
    const float* Wo    = (const float*)d_in[4];
    const float* gamma = (const float*)d_in[5];
    const float* beta  = (const float*)d_in[6];
    float* out = (float*)d_out;

    float* ws     = (float*)d_ws;
    float* qk_raw = ws;                          // 4096*512
    float* vbuf   = qk_raw + 4096 * 512;         // 4096*1024
    float* obuf   = vbuf + 4096 * 1024;          // 4096*1024
    (void)in_sizes; (void)n_in; (void)out_size; (void)ws_size;

    // q|k projection: C[4096][512], cols 0..255 = Wq rows, 256..511 = Wk rows
    gemm_nt<<<dim3(32, 4), 256, 0, stream>>>(x, Wq, Wk, qk_raw, 4096, 512, 1024, 256);
    // v projection
    gemm_nt<<<dim3(32, 8), 256, 0, stream>>>(x, Wv, Wv, vbuf, 4096, 1024, 1024, 1024);
    // feature map (in place on qk_raw)
    ln_featuremap<<<512, 256, 0, stream>>>(qk_raw, gamma, beta);
    // causal (q.k)^2 attention -> obuf in (b, l, h*64+d) layout
    rebased_attn<<<dim3(16, 32), 256, 0, stream>>>(qk_raw, vbuf, obuf);
    // output projection
    gemm_nt<<<dim3(32, 8), 256, 0, stream>>>(obuf, Wo, Wo, out, 4096, 1024, 1024, 1024);
}

// Round 4
// 275.673 us; speedup vs baseline: 2.6601x; 2.6601x over previous
//
#include <hip/hip_runtime.h>
#include <cstddef>
#include <cstdint>

// ReBased linear attention, round 4.
// Round-3 accuracy fail (3.35e-2 > 2.5e-2) root-caused to bf16 q/k projection:
// s = (q.k)^2 doubles relative error. Fix: split-bf16 (hi+lo) GEMM for the qk
// projection only (x_hi*W_hi + x_hi*W_lo + x_lo*W_hi ~= fp32). v / Wo GEMMs
// stay plain bf16 MFMA (linear error paths, ~0.36%/0.3%).

typedef __attribute__((ext_vector_type(8)))  __bf16 bf16x8;
typedef __attribute__((ext_vector_type(4)))  float  f32x4;
typedef __attribute__((ext_vector_type(8)))  unsigned short ushort8;
typedef __attribute__((ext_vector_type(4)))  unsigned short ushort4v;

__device__ __forceinline__ unsigned short f2b(float f) {
    union { float f; unsigned u; } v; v.f = f;
    unsigned r = v.u + 0x7FFFu + ((v.u >> 16) & 1u);   // RNE
    return (unsigned short)(r >> 16);
}
__device__ __forceinline__ float b2f(unsigned short b) {
    union { unsigned u; float f; } v; v.u = ((unsigned)b) << 16;
    return v.f;
}

typedef const __attribute__((address_space(1))) void* gas_ptr;
typedef __attribute__((address_space(3))) void* las_ptr;

__device__ __forceinline__ void gload_lds16(const unsigned short* g, unsigned short* l) {
    // 16B per lane, LDS dest = wave-uniform base + lane*16 (pass wave base!)
    __builtin_amdgcn_global_load_lds((gas_ptr)g, (las_ptr)l, 16, 0, 0);
}

// ---------------- bf16 MFMA GEMM: C[M][N] = A[M][K] @ W[N][K]^T ----------------
// BM=128 fixed, BN in {64,128}. 256 threads = 4 waves (2x2), per-wave 64 x BN/2.
template <int BN, bool OUTB>
__global__ __launch_bounds__(256) void gemm_mfma(const unsigned short* __restrict__ A,
                                                 const unsigned short* __restrict__ W,
                                                 void* __restrict__ Cout,
                                                 int M, int N, int K) {
    constexpr int BM = 128, BK = 64;
    constexpr int NF = BN / 32;
    __shared__ __align__(16) unsigned short As[BM * BK];
    __shared__ __align__(16) unsigned short Bs[BN * BK];

    const int t = threadIdx.x;
    const int wid = t >> 6, lane = t & 63;
    const int m0 = blockIdx.x * BM, n0 = blockIdx.y * BN;
    const int wrow = (wid >> 1) * 64;
    const int wcol = (wid & 1) * (BN / 2);
    const int lr = lane & 15, lk = (lane >> 4) * 8;

    f32x4 acc[4][NF];
#pragma unroll
    for (int m = 0; m < 4; ++m)
#pragma unroll
        for (int n = 0; n < NF; ++n) acc[m][n] = (f32x4){0.f, 0.f, 0.f, 0.f};

    const unsigned short* Ag = A + (size_t)m0 * K;
    const unsigned short* Wg = W + (size_t)n0 * K;

    for (int k0 = 0; k0 < K; k0 += BK) {
        __syncthreads();
#pragma unroll
        for (int i = 0; i < BM / 32; ++i) {
            const int e = (i * 256 + wid * 64 + lane) * 8;
            gload_lds16(Ag + (size_t)(e >> 6) * K + k0 + (e & 63),
                        As + (size_t)(i * 256 + wid * 64) * 8);
        }
#pragma unroll
        for (int i = 0; i < BN / 32; ++i) {
            const int e = (i * 256 + wid * 64 + lane) * 8;
            gload_lds16(Wg + (size_t)(e >> 6) * K + k0 + (e & 63),
                        Bs + (size_t)(i * 256 + wid * 64) * 8);
        }
        __syncthreads();

#pragma unroll
        for (int kk = 0; kk < BK; kk += 32) {
            bf16x8 af[4], bf[NF];
#pragma unroll
            for (int m = 0; m < 4; ++m)
                af[m] = *(const bf16x8*)&As[(wrow + m * 16 + lr) * BK + kk + lk];
#pragma unroll
            for (int n = 0; n < NF; ++n)
                bf[n] = *(const bf16x8*)&Bs[(wcol + n * 16 + lr) * BK + kk + lk];
#pragma unroll
            for (int m = 0; m < 4; ++m)
#pragma unroll
                for (int n = 0; n < NF; ++n)
                    acc[m][n] = __builtin_amdgcn_mfma_f32_16x16x32_bf16(af[m], bf[n], acc[m][n], 0, 0, 0);
        }
    }

    const int orow0 = m0 + wrow + (lane >> 4) * 4;
    const int ocol0 = n0 + wcol + lr;
#pragma unroll
    for (int m = 0; m < 4; ++m)
#pragma unroll
        for (int n = 0; n < NF; ++n)
#pragma unroll
            for (int i = 0; i < 4; ++i) {
                const size_t idx = (size_t)(orow0 + m * 16 + i) * N + ocol0 + n * 16;
                if (OUTB) ((unsigned short*)Cout)[idx] = f2b(acc[m][n][i]);
                else      ((float*)Cout)[idx] = acc[m][n][i];
            }
}

// ------------- split-bf16 GEMM (qk projection): ~fp32 via hi/lo -------------
// C = (Ah+Al) @ (Wh+Wl)^T approx= Ah@Wh + Ah@Wl + Al@Wh. BM=128, BN=64, BK=64.
__global__ __launch_bounds__(256) void gemm_split(const unsigned short* __restrict__ Ah,
                                                  const unsigned short* __restrict__ Al,
                                                  const unsigned short* __restrict__ Wh,
                                                  const unsigned short* __restrict__ Wl,
                                                  float* __restrict__ C,
                                                  int M, int N, int K) {
    constexpr int BM = 128, BN = 64, BK = 64;
    constexpr int NF = BN / 32;    // 2
    __shared__ __align__(16) unsigned short Ahs[BM * BK];
    __shared__ __align__(16) unsigned short Als[BM * BK];
    __shared__ __align__(16) unsigned short Bhs[BN * BK];
    __shared__ __align__(16) unsigned short Bls[BN * BK];

    const int t = threadIdx.x;
    const int wid = t >> 6, lane = t & 63;
    const int m0 = blockIdx.x * BM, n0 = blockIdx.y * BN;
    const int wrow = (wid >> 1) * 64;
    const int wcol = (wid & 1) * (BN / 2);
    const int lr = lane & 15, lk = (lane >> 4) * 8;

    f32x4 acc[4][NF];
#pragma unroll
    for (int m = 0; m < 4; ++m)
#pragma unroll
        for (int n = 0; n < NF; ++n) acc[m][n] = (f32x4){0.f, 0.f, 0.f, 0.f};

    const unsigned short* Ahg = Ah + (size_t)m0 * K;
    const unsigned short* Alg = Al + (size_t)m0 * K;
    const unsigned short* Whg = Wh + (size_t)n0 * K;
    const unsigned short* Wlg = Wl + (size_t)n0 * K;

    for (int k0 = 0; k0 < K; k0 += BK) {
        __syncthreads();
#pragma unroll
        for (int i = 0; i < BM / 32; ++i) {
            const int e = (i * 256 + wid * 64 + lane) * 8;
            const size_t go = (size_t)(e >> 6) * K + k0 + (e & 63);
            const size_t lo = (size_t)(i * 256 + wid * 64) * 8;
            gload_lds16(Ahg + go, Ahs + lo);
            gload_lds16(Alg + go, Als + lo);
        }
#pragma unroll
        for (int i = 0; i < BN / 32; ++i) {
            const int e = (i * 256 + wid * 64 + lane) * 8;
            const size_t go = (size_t)(e >> 6) * K + k0 + (e & 63);
            const size_t lo = (size_t)(i * 256 + wid * 64) * 8;
            gload_lds16(Whg + go, Bhs + lo);
            gload_lds16(Wlg + go, Bls + lo);
        }
        __syncthreads();

#pragma unroll
        for (int kk = 0; kk < BK; kk += 32) {
            bf16x8 afh[4], afl[4], bfh[NF], bfl[NF];
#pragma unroll
            for (int m = 0; m < 4; ++m) {
                afh[m] = *(const bf16x8*)&Ahs[(wrow + m * 16 + lr) * BK + kk + lk];
                afl[m] = *(const bf16x8*)&Als[(wrow + m * 16 + lr) * BK + kk + lk];
            }
#pragma unroll
            for (int n = 0; n < NF; ++n) {
                bfh[n] = *(const bf16x8*)&Bhs[(wcol + n * 16 + lr) * BK + kk + lk];
                bfl[n] = *(const bf16x8*)&Bls[(wcol + n * 16 + lr) * BK + kk + lk];
            }
#pragma unroll
            for (int m = 0; m < 4; ++m)
#pragma unroll
                for (int n = 0; n < NF; ++n) {
                    acc[m][n] = __builtin_amdgcn_mfma_f32_16x16x32_bf16(afh[m], bfh[n], acc[m][n], 0, 0, 0);
                    acc[m][n] = __builtin_amdgcn_mfma_f32_16x16x32_bf16(afh[m], bfl[n], acc[m][n], 0, 0, 0);
                    acc[m][n] = __builtin_amdgcn_mfma_f32_16x16x32_bf16(afl[m], bfh[n], acc[m][n], 0, 0, 0);
                }
        }
    }

    const int orow0 = m0 + wrow + (lane >> 4) * 4;
    const int ocol0 = n0 + wcol + lr;
#pragma unroll
    for (int m = 0; m < 4; ++m)
#pragma unroll
        for (int n = 0; n < NF; ++n)
#pragma unroll
            for (int i = 0; i < 4; ++i)
                C[(size_t)(orow0 + m * 16 + i) * N + ocol0 + n * 16] = acc[m][n][i];
}

// ---------------- f32 -> bf16 casts ----------------
__global__ __launch_bounds__(256) void cast_bf16(const float* __restrict__ in,
                                                 unsigned short* __restrict__ out, int n) {
    const int i = (blockIdx.x * 256 + threadIdx.x) * 8;
    if (i >= n) return;
    float4 a = *(const float4*)(in + i);
    float4 b = *(const float4*)(in + i + 4);
    ushort8 o;
    o[0] = f2b(a.x); o[1] = f2b(a.y); o[2] = f2b(a.z); o[3] = f2b(a.w);
    o[4] = f2b(b.x); o[5] = f2b(b.y); o[6] = f2b(b.z); o[7] = f2b(b.w);
    *(ushort8*)(out + i) = o;
}

// hi = bf16(x), lo = bf16(x - hi)
__global__ __launch_bounds__(256) void cast_split(const float* __restrict__ in,
                                                  unsigned short* __restrict__ hi,
                                                  unsigned short* __restrict__ lo, int n) {
    const int i = (blockIdx.x * 256 + threadIdx.x) * 8;
    if (i >= n) return;
    float4 a = *(const float4*)(in + i);
    float4 b = *(const float4*)(in + i + 4);
    float xv[8] = {a.x, a.y, a.z, a.w, b.x, b.y, b.z, b.w};
    ushort8 oh, ol;
#pragma unroll
    for (int e = 0; e < 8; ++e) {
        const unsigned short h = f2b(xv[e]);
        oh[e] = h;
        ol[e] = f2b(xv[e] - b2f(h));
    }
    *(ushort8*)(hi + i) = oh;
    *(ushort8*)(lo + i) = ol;
}

// ---------------- feature map (in-place on fp32 qk_raw) ----------------
__global__ __launch_bounds__(256) void ln_featuremap(float* __restrict__ qk,
                                                     const float* __restrict__ gamma,
                                                     const float* __restrict__ beta) {
    const int gid = blockIdx.x * 256 + threadIdx.x;
    const int idx = gid & 31;
    float* p = qk + (size_t)gid * 16;
    const float scale = (idx < 16) ? 0.25f : 1.0f;

    float xv[16];
    float4 v0 = *(const float4*)(p + 0);
    float4 v1 = *(const float4*)(p + 4);
    float4 v2 = *(const float4*)(p + 8);
    float4 v3 = *(const float4*)(p + 12);
    xv[0]=v0.x; xv[1]=v0.y; xv[2]=v0.z; xv[3]=v0.w;
    xv[4]=v1.x; xv[5]=v1.y; xv[6]=v1.z; xv[7]=v1.w;
    xv[8]=v2.x; xv[9]=v2.y; xv[10]=v2.z; xv[11]=v2.w;
    xv[12]=v3.x; xv[13]=v3.y; xv[14]=v3.z; xv[15]=v3.w;

    float mu = 0.f;
#pragma unroll
    for (int f = 0; f < 16; ++f) mu += xv[f];
    mu *= 0.0625f;
    float var = 0.f;
#pragma unroll
    for (int f = 0; f < 16; ++f) { float d = xv[f] - mu; var = fmaf(d, d, var); }
    var *= 0.0625f;
    const float rs = rsqrtf(var + 1e-5f);
#pragma unroll
    for (int f = 0; f < 16; ++f)
        xv[f] = ((xv[f] - mu) * rs * gamma[f] + beta[f]) * scale;

    *(float4*)(p + 0)  = make_float4(xv[0], xv[1], xv[2], xv[3]);
    *(float4*)(p + 4)  = make_float4(xv[4], xv[5], xv[6], xv[7]);
    *(float4*)(p + 8)  = make_float4(xv[8], xv[9], xv[10], xv[11]);
    *(float4*)(p + 12) = make_float4(xv[12], xv[13], xv[14], xv[15]);
}

// ---------------- causal (q.k)^2 attention, fp32 VALU, bf16 v/o ----------------
__global__ __launch_bounds__(256) void rebased_attn(const float* __restrict__ qk,
                                                    const unsigned short* __restrict__ v,
                                                    unsigned short* __restrict__ o) {
    const int bh = blockIdx.y;
    const int bb = bh >> 4, h = bh & 15;
    const int t = threadIdx.x;
    const int tr4 = (t >> 4) << 2;
    const int tc4 = (t & 15) << 2;

    __shared__ __align__(16) float qT[16][68];
    __shared__ __align__(16) float kT[16][68];
    __shared__ __align__(16) float sT[64][68];
    __shared__ __align__(16) float vs[64][68];
    __shared__ float zp[64][17];
    __shared__ float zf[64];

    const float*          qbh = qk + (size_t)bb * 2048 * 512 + h * 16;
    const float*          kbh = qk + (size_t)bb * 2048 * 512 + 256 + h * 16;
    const unsigned short* vbh = v  + (size_t)bb * 2048 * 1024 + h * 64;
    unsigned short*       obh = o  + (size_t)bb * 2048 * 1024 + h * 64;

    const int ldj = t >> 2;
    const int lf4 = (t & 3) << 2;
    const int lc16 = (t & 3) << 4;

    for (int pass = 0; pass < 2; ++pass) {
        const int qt = pass ? (31 - (int)blockIdx.x) : (int)blockIdx.x;
        const int qbase = qt << 6;

        {
            float4 qv = *(const float4*)&qbh[(size_t)(qbase + ldj) * 512 + lf4];
            qT[lf4 + 0][ldj] = qv.x; qT[lf4 + 1][ldj] = qv.y;
            qT[lf4 + 2][ldj] = qv.z; qT[lf4 + 3][ldj] = qv.w;
        }

        float oa[4][4];
        float zrow[4];
#pragma unroll
        for (int i = 0; i < 4; ++i) {
            zrow[i] = 0.f;
#pragma unroll
            for (int j = 0; j < 4; ++j) oa[i][j] = 0.f;
        }

        for (int kt = 0; kt <= qt; ++kt) {
            __syncthreads();
            {
                float4 kv = *(const float4*)&kbh[(size_t)((kt << 6) + ldj) * 512 + lf4];
                kT[lf4 + 0][ldj] = kv.x; kT[lf4 + 1][ldj] = kv.y;
                kT[lf4 + 2][ldj] = kv.z; kT[lf4 + 3][ldj] = kv.w;
                ushort8 r0 = *(const ushort8*)&vbh[(size_t)((kt << 6) + ldj) * 1024 + lc16];
                ushort8 r1 = *(const ushort8*)&vbh[(size_t)((kt << 6) + ldj) * 1024 + lc16 + 8];
#pragma unroll
                for (int e = 0; e < 8; ++e) {
                    vs[ldj][lc16 + e]     = b2f(r0[e]);
                    vs[ldj][lc16 + 8 + e] = b2f(r1[e]);
                }
            }
            __syncthreads();

            float sa[4][4];
#pragma unroll
            for (int i = 0; i < 4; ++i)
#pragma unroll
                for (int j = 0; j < 4; ++j) sa[i][j] = 0.f;
#pragma unroll
            for (int f = 0; f < 16; ++f) {
                float4 a4 = *(const float4*)&qT[f][tr4];
                float4 b4 = *(const float4*)&kT[f][tc4];
                float av[4] = {a4.x, a4.y, a4.z, a4.w};
                float bv[4] = {b4.x, b4.y, b4.z, b4.w};
#pragma unroll
                for (int i = 0; i < 4; ++i)
#pragma unroll
                    for (int j = 0; j < 4; ++j)
                        sa[i][j] = fmaf(av[i], bv[j], sa[i][j]);
            }
#pragma unroll
            for (int j = 0; j < 4; ++j) {
                const int col = (kt << 6) + tc4 + j;
                float sv[4];
#pragma unroll
                for (int i = 0; i < 4; ++i) {
                    const int row = qbase + tr4 + i;
                    const float d = sa[i][j];
                    const float s2 = (col <= row) ? d * d : 0.f;
                    sv[i] = s2;
                    zrow[i] += s2;
                }
                *(float4*)&sT[tc4 + j][tr4] = make_float4(sv[0], sv[1], sv[2], sv[3]);
            }
            __syncthreads();

#pragma unroll 4
            for (int j = 0; j < 64; ++j) {
                float4 a4 = *(const float4*)&sT[j][tr4];
                float4 b4 = *(const float4*)&vs[j][tc4];
                float av[4] = {a4.x, a4.y, a4.z, a4.w};
                float bv[4] = {b4.x, b4.y, b4.z, b4.w};
#pragma unroll
                for (int i = 0; i < 4; ++i)
#pragma unroll
                    for (int cj = 0; cj < 4; ++cj)
                        oa[i][cj] = fmaf(av[i], bv[cj], oa[i][cj]);
            }
        }

        __syncthreads();
#pragma unroll
        for (int i = 0; i < 4; ++i) zp[tr4 + i][t & 15] = zrow[i];
        __syncthreads();
        if (t < 64) {
            float s = 1e-5f;
#pragma unroll
            for (int c = 0; c < 16; ++c) s += zp[t][c];
            zf[t] = 1.f / s;
        }
        __syncthreads();
#pragma unroll
        for (int i = 0; i < 4; ++i) {
            const float r = zf[tr4 + i];
            ushort4v ov;
            ov[0] = f2b(oa[i][0] * r); ov[1] = f2b(oa[i][1] * r);
            ov[2] = f2b(oa[i][2] * r); ov[3] = f2b(oa[i][3] * r);
            *(ushort4v*)&obh[(size_t)(qbase + tr4 + i) * 1024 + tc4] = ov;
        }
        __syncthreads();
    }
}

extern "C" void kernel_launch(void* const* d_in, const int* in_sizes, int n_in,
                              void* d_out, int out_size, void* d_ws, size_t ws_size,
                              hipStream_t stream) {
    const float* x     = (const float*)d_in[0];
    const float* Wq    = (const float*)d_in[1];
    const float* Wk    = (const float*)d_in[2];
    const float* Wv    = (const float*)d_in[3];
    const float* Wo    = (const float*)d_in[4];
    const float* gamma = (const float*)d_in[5];
    const float* beta  = (const float*)d_in[6];
    float* out = (float*)d_out;
    (void)in_sizes; (void)n_in; (void)out_size; (void)ws_size;

    char* w = (char*)d_ws;
    float*          qk_raw = (float*)w;                                   // 8 MB @ 0
    unsigned short* vb     = (unsigned short*)(w + (8u  << 20));          // 8 MB
    unsigned short* ob     = (unsigned short*)(w + (16u << 20));          // 8 MB
    unsigned short* xh     = (unsigned short*)(w + (24u << 20));          // 8 MB
    unsigned short* xl     = (unsigned short*)(w + (32u << 20));          // 8 MB
    unsigned short* wqkh   = (unsigned short*)(w + (40u << 20));          // 1 MB
    unsigned short* wqkl   = (unsigned short*)(w + (41u << 20));          // 1 MB
    unsigned short* wvb    = (unsigned short*)(w + (42u << 20));          // 2 MB
    unsigned short* wob    = (unsigned short*)(w + (44u << 20));          // 2 MB

    // casts: x and Wq/Wk split hi/lo (qk path), Wv/Wo plain bf16
    cast_split<<<2048, 256, 0, stream>>>(x,  xh, xl, 4096 * 1024);
    cast_split<<<128,  256, 0, stream>>>(Wq, wqkh, wqkl, 256 * 1024);
    cast_split<<<128,  256, 0, stream>>>(Wk, wqkh + 256 * 1024, wqkl + 256 * 1024, 256 * 1024);
    cast_bf16 <<<512,  256, 0, stream>>>(Wv, wvb, 1024 * 1024);
    cast_bf16 <<<512,  256, 0, stream>>>(Wo, wob, 1024 * 1024);

    // qk projection, ~fp32 via split-bf16: [4096][512] f32
    gemm_split<<<dim3(32, 8), 256, 0, stream>>>(xh, xl, wqkh, wqkl, qk_raw, 4096, 512, 1024);
    // v projection -> bf16
    gemm_mfma<128, true><<<dim3(32, 8), 256, 0, stream>>>(xh, wvb, vb, 4096, 1024, 1024);
    // feature map in-place
    ln_featuremap<<<512, 256, 0, stream>>>(qk_raw, gamma, beta);
    // attention -> bf16 obuf (b, l, h*64+d)
    rebased_attn<<<dim3(16, 32), 256, 0, stream>>>(qk_raw, vb, ob);
    // output projection -> f32 out
    gemm_mfma<128, false><<<dim3(32, 8), 256, 0, stream>>>(ob, wob, out, 4096, 1024, 1024);
}

// Round 5
// 167.110 us; speedup vs baseline: 4.3883x; 1.6497x over previous
//
#include <hip/hip_runtime.h>
#include <cstddef>
#include <cstdint>

// ReBased linear attention, round 5: attention phase-2 (S@V) on MFMA.
// - v GEMM writes transposed vT[b*16+h][d][l] bf16 (B-frag-friendly).
// - attn phase1 stays fp32 VALU (accuracy), writes P=S^2 as bf16 [row][col]
//   (contiguous 8B packs, conflict-free; replaces 8-way-conflict sT writes).
// - attn phase2: 8x mfma_f32_16x16x32_bf16 per wave per k-tile.

typedef __attribute__((ext_vector_type(8)))  __bf16 bf16x8;
typedef __attribute__((ext_vector_type(4)))  float  f32x4;
typedef __attribute__((ext_vector_type(8)))  unsigned short ushort8;
typedef __attribute__((ext_vector_type(4)))  unsigned short ushort4v;

__device__ __forceinline__ unsigned short f2b(float f) {
    union { float f; unsigned u; } v; v.f = f;
    unsigned r = v.u + 0x7FFFu + ((v.u >> 16) & 1u);   // RNE
    return (unsigned short)(r >> 16);
}
__device__ __forceinline__ float b2f(unsigned short b) {
    union { unsigned u; float f; } v; v.u = ((unsigned)b) << 16;
    return v.f;
}

typedef const __attribute__((address_space(1))) void* gas_ptr;
typedef __attribute__((address_space(3))) void* las_ptr;

__device__ __forceinline__ void gload_lds16(const unsigned short* g, unsigned short* l) {
    __builtin_amdgcn_global_load_lds((gas_ptr)g, (las_ptr)l, 16, 0, 0);
}

// ---------------- bf16 MFMA GEMM: C[M][N] = A[M][K] @ W[N][K]^T ----------------
// OUTMODE: 0 = f32 row-major, 1 = bf16 row-major, 2 = bf16 transposed vT scatter
// vT layout: [(m>>11)*16 + (n>>6)][n&63][m&2047]  i.e. [b*16+h][d][l]
template <int BN, int OUTMODE>
__global__ __launch_bounds__(256) void gemm_mfma(const unsigned short* __restrict__ A,
                                                 const unsigned short* __restrict__ W,
                                                 void* __restrict__ Cout,
                                                 int M, int N, int K) {
    constexpr int BM = 128, BK = 64;
    constexpr int NF = BN / 32;
    __shared__ __align__(16) unsigned short As[BM * BK];
    __shared__ __align__(16) unsigned short Bs[BN * BK];

    const int t = threadIdx.x;
    const int wid = t >> 6, lane = t & 63;
    const int m0 = blockIdx.x * BM, n0 = blockIdx.y * BN;
    const int wrow = (wid >> 1) * 64;
    const int wcol = (wid & 1) * (BN / 2);
    const int lr = lane & 15, lk = (lane >> 4) * 8;

    f32x4 acc[4][NF];
#pragma unroll
    for (int m = 0; m < 4; ++m)
#pragma unroll
        for (int n = 0; n < NF; ++n) acc[m][n] = (f32x4){0.f, 0.f, 0.f, 0.f};

    const unsigned short* Ag = A + (size_t)m0 * K;
    const unsigned short* Wg = W + (size_t)n0 * K;

    for (int k0 = 0; k0 < K; k0 += BK) {
        __syncthreads();
#pragma unroll
        for (int i = 0; i < BM / 32; ++i) {
            const int e = (i * 256 + wid * 64 + lane) * 8;
            gload_lds16(Ag + (size_t)(e >> 6) * K + k0 + (e & 63),
                        As + (size_t)(i * 256 + wid * 64) * 8);
        }
#pragma unroll
        for (int i = 0; i < BN / 32; ++i) {
            const int e = (i * 256 + wid * 64 + lane) * 8;
            gload_lds16(Wg + (size_t)(e >> 6) * K + k0 + (e & 63),
                        Bs + (size_t)(i * 256 + wid * 64) * 8);
        }
        __syncthreads();

#pragma unroll
        for (int kk = 0; kk < BK; kk += 32) {
            bf16x8 af[4], bf[NF];
#pragma unroll
            for (int m = 0; m < 4; ++m)
                af[m] = *(const bf16x8*)&As[(wrow + m * 16 + lr) * BK + kk + lk];
#pragma unroll
            for (int n = 0; n < NF; ++n)
                bf[n] = *(const bf16x8*)&Bs[(wcol + n * 16 + lr) * BK + kk + lk];
#pragma unroll
            for (int m = 0; m < 4; ++m)
#pragma unroll
                for (int n = 0; n < NF; ++n)
                    acc[m][n] = __builtin_amdgcn_mfma_f32_16x16x32_bf16(af[m], bf[n], acc[m][n], 0, 0, 0);
        }
    }

    const int orow0 = m0 + wrow + (lane >> 4) * 4;
    const int ocol0 = n0 + wcol + lr;
#pragma unroll
    for (int m = 0; m < 4; ++m)
#pragma unroll
        for (int n = 0; n < NF; ++n) {
            if (OUTMODE == 2) {
                const int nc = ocol0 + n * 16;
                const int mrow = orow0 + m * 16;
                unsigned short* dst = (unsigned short*)Cout
                    + (size_t)((mrow >> 11) * 16 + (nc >> 6)) * (64 * 2048)
                    + (size_t)(nc & 63) * 2048 + (mrow & 2047);
                ushort4v pv;
#pragma unroll
                for (int i = 0; i < 4; ++i) pv[i] = f2b(acc[m][n][i]);
                *(ushort4v*)dst = pv;   // 4 consecutive l
            } else {
#pragma unroll
                for (int i = 0; i < 4; ++i) {
                    const size_t idx = (size_t)(orow0 + m * 16 + i) * N + ocol0 + n * 16;
                    if (OUTMODE == 1) ((unsigned short*)Cout)[idx] = f2b(acc[m][n][i]);
                    else              ((float*)Cout)[idx] = acc[m][n][i];
                }
            }
        }
}

// ------------- split-bf16 GEMM (qk projection): ~fp32 via hi/lo -------------
__global__ __launch_bounds__(256) void gemm_split(const unsigned short* __restrict__ Ah,
                                                  const unsigned short* __restrict__ Al,
                                                  const unsigned short* __restrict__ Wh,
                                                  const unsigned short* __restrict__ Wl,
                                                  float* __restrict__ C,
                                                  int M, int N, int K) {
    constexpr int BM = 128, BN = 64, BK = 64;
    constexpr int NF = BN / 32;
    __shared__ __align__(16) unsigned short Ahs[BM * BK];
    __shared__ __align__(16) unsigned short Als[BM * BK];
    __shared__ __align__(16) unsigned short Bhs[BN * BK];
    __shared__ __align__(16) unsigned short Bls[BN * BK];

    const int t = threadIdx.x;
    const int wid = t >> 6, lane = t & 63;
    const int m0 = blockIdx.x * BM, n0 = blockIdx.y * BN;
    const int wrow = (wid >> 1) * 64;
    const int wcol = (wid & 1) * (BN / 2);
    const int lr = lane & 15, lk = (lane >> 4) * 8;

    f32x4 acc[4][NF];
#pragma unroll
    for (int m = 0; m < 4; ++m)
#pragma unroll
        for (int n = 0; n < NF; ++n) acc[m][n] = (f32x4){0.f, 0.f, 0.f, 0.f};

    const unsigned short* Ahg = Ah + (size_t)m0 * K;
    const unsigned short* Alg = Al + (size_t)m0 * K;
    const unsigned short* Whg = Wh + (size_t)n0 * K;
    const unsigned short* Wlg = Wl + (size_t)n0 * K;

    for (int k0 = 0; k0 < K; k0 += BK) {
        __syncthreads();
#pragma unroll
        for (int i = 0; i < BM / 32; ++i) {
            const int e = (i * 256 + wid * 64 + lane) * 8;
            const size_t go = (size_t)(e >> 6) * K + k0 + (e & 63);
            const size_t lo = (size_t)(i * 256 + wid * 64) * 8;
            gload_lds16(Ahg + go, Ahs + lo);
            gload_lds16(Alg + go, Als + lo);
        }
#pragma unroll
        for (int i = 0; i < BN / 32; ++i) {
            const int e = (i * 256 + wid * 64 + lane) * 8;
            const size_t go = (size_t)(e >> 6) * K + k0 + (e & 63);
            const size_t lo = (size_t)(i * 256 + wid * 64) * 8;
            gload_lds16(Whg + go, Bhs + lo);
            gload_lds16(Wlg + go, Bls + lo);
        }
        __syncthreads();

#pragma unroll
        for (int kk = 0; kk < BK; kk += 32) {
            bf16x8 afh[4], afl[4], bfh[NF], bfl[NF];
#pragma unroll
            for (int m = 0; m < 4; ++m) {
                afh[m] = *(const bf16x8*)&Ahs[(wrow + m * 16 + lr) * BK + kk + lk];
                afl[m] = *(const bf16x8*)&Als[(wrow + m * 16 + lr) * BK + kk + lk];
            }
#pragma unroll
            for (int n = 0; n < NF; ++n) {
                bfh[n] = *(const bf16x8*)&Bhs[(wcol + n * 16 + lr) * BK + kk + lk];
                bfl[n] = *(const bf16x8*)&Bls[(wcol + n * 16 + lr) * BK + kk + lk];
            }
#pragma unroll
            for (int m = 0; m < 4; ++m)
#pragma unroll
                for (int n = 0; n < NF; ++n) {
                    acc[m][n] = __builtin_amdgcn_mfma_f32_16x16x32_bf16(afh[m], bfh[n], acc[m][n], 0, 0, 0);
                    acc[m][n] = __builtin_amdgcn_mfma_f32_16x16x32_bf16(afh[m], bfl[n], acc[m][n], 0, 0, 0);
                    acc[m][n] = __builtin_amdgcn_mfma_f32_16x16x32_bf16(afl[m], bfh[n], acc[m][n], 0, 0, 0);
                }
        }
    }

    const int orow0 = m0 + wrow + (lane >> 4) * 4;
    const int ocol0 = n0 + wcol + lr;
#pragma unroll
    for (int m = 0; m < 4; ++m)
#pragma unroll
        for (int n = 0; n < NF; ++n)
#pragma unroll
            for (int i = 0; i < 4; ++i)
                C[(size_t)(orow0 + m * 16 + i) * N + ocol0 + n * 16] = acc[m][n][i];
}

// ---------------- f32 -> bf16 casts ----------------
__global__ __launch_bounds__(256) void cast_bf16(const float* __restrict__ in,
                                                 unsigned short* __restrict__ out, int n) {
    const int i = (blockIdx.x * 256 + threadIdx.x) * 8;
    if (i >= n) return;
    float4 a = *(const float4*)(in + i);
    float4 b = *(const float4*)(in + i + 4);
    ushort8 o;
    o[0] = f2b(a.x); o[1] = f2b(a.y); o[2] = f2b(a.z); o[3] = f2b(a.w);
    o[4] = f2b(b.x); o[5] = f2b(b.y); o[6] = f2b(b.z); o[7] = f2b(b.w);
    *(ushort8*)(out + i) = o;
}

__global__ __launch_bounds__(256) void cast_split(const float* __restrict__ in,
                                                  unsigned short* __restrict__ hi,
                                                  unsigned short* __restrict__ lo, int n) {
    const int i = (blockIdx.x * 256 + threadIdx.x) * 8;
    if (i >= n) return;
    float4 a = *(const float4*)(in + i);
    float4 b = *(const float4*)(in + i + 4);
    float xv[8] = {a.x, a.y, a.z, a.w, b.x, b.y, b.z, b.w};
    ushort8 oh, ol;
#pragma unroll
    for (int e = 0; e < 8; ++e) {
        const unsigned short h = f2b(xv[e]);
        oh[e] = h;
        ol[e] = f2b(xv[e] - b2f(h));
    }
    *(ushort8*)(hi + i) = oh;
    *(ushort8*)(lo + i) = ol;
}

// ---------------- feature map (in-place on fp32 qk_raw) ----------------
__global__ __launch_bounds__(256) void ln_featuremap(float* __restrict__ qk,
                                                     const float* __restrict__ gamma,
                                                     const float* __restrict__ beta) {
    const int gid = blockIdx.x * 256 + threadIdx.x;
    const int idx = gid & 31;
    float* p = qk + (size_t)gid * 16;
    const float scale = (idx < 16) ? 0.25f : 1.0f;

    float xv[16];
    float4 v0 = *(const float4*)(p + 0);
    float4 v1 = *(const float4*)(p + 4);
    float4 v2 = *(const float4*)(p + 8);
    float4 v3 = *(const float4*)(p + 12);
    xv[0]=v0.x; xv[1]=v0.y; xv[2]=v0.z; xv[3]=v0.w;
    xv[4]=v1.x; xv[5]=v1.y; xv[6]=v1.z; xv[7]=v1.w;
    xv[8]=v2.x; xv[9]=v2.y; xv[10]=v2.z; xv[11]=v2.w;
    xv[12]=v3.x; xv[13]=v3.y; xv[14]=v3.z; xv[15]=v3.w;

    float mu = 0.f;
#pragma unroll
    for (int f = 0; f < 16; ++f) mu += xv[f];
    mu *= 0.0625f;
    float var = 0.f;
#pragma unroll
    for (int f = 0; f < 16; ++f) { float d = xv[f] - mu; var = fmaf(d, d, var); }
    var *= 0.0625f;
    const float rs = rsqrtf(var + 1e-5f);
#pragma unroll
    for (int f = 0; f < 16; ++f)
        xv[f] = ((xv[f] - mu) * rs * gamma[f] + beta[f]) * scale;

    *(float4*)(p + 0)  = make_float4(xv[0], xv[1], xv[2], xv[3]);
    *(float4*)(p + 4)  = make_float4(xv[4], xv[5], xv[6], xv[7]);
    *(float4*)(p + 8)  = make_float4(xv[8], xv[9], xv[10], xv[11]);
    *(float4*)(p + 12) = make_float4(xv[12], xv[13], xv[14], xv[15]);
}

// ------- causal (q.k)^2 attention: VALU phase1 + MFMA phase2 -------
// grid (16, 32). vT layout [b*16+h][64 d][2048 l] bf16.
__global__ __launch_bounds__(256) void rebased_attn(const float* __restrict__ qk,
                                                    const unsigned short* __restrict__ vT,
                                                    unsigned short* __restrict__ o) {
    const int bh = blockIdx.y;
    const int bb = bh >> 4, h = bh & 15;
    const int t = threadIdx.x;
    const int wid = t >> 6, lane = t & 63;
    const int tr4 = (t >> 4) << 2;      // phase1 rows (16*wid + 4*(lane>>4))
    const int tc4 = (t & 15) << 2;      // phase1 cols
    const int fr = lane & 15;           // frag row
    const int fg = lane >> 4;           // frag k-group

    __shared__ __align__(16) float qT[16][68];
    __shared__ __align__(16) float kT[16][68];
    __shared__ __align__(16) unsigned short P[64][72];   // S^2 bf16 [q-row][k-col]
    __shared__ __align__(16) unsigned short vs[64][72];  // V^T tile [d][k-col]
    __shared__ float zp[64][17];
    __shared__ float zf[64];

    const float*          qbh = qk + (size_t)bb * 2048 * 512 + h * 16;
    const float*          kbh = qk + (size_t)bb * 2048 * 512 + 256 + h * 16;
    const unsigned short* vbh = vT + (size_t)bh * 64 * 2048;
    unsigned short*       obh = o  + (size_t)bb * 2048 * 1024 + h * 64;

    const int ldj = t >> 2;             // k-loader row 0..63
    const int lf4 = (t & 3) << 2;       // 0,4,8,12
    const int vd  = t >> 2;             // v-stage d row 0..63
    const int vc16 = (t & 3) << 4;      // v-stage col chunk 0,16,32,48

    for (int pass = 0; pass < 2; ++pass) {
        const int qt = pass ? (31 - (int)blockIdx.x) : (int)blockIdx.x;
        const int qbase = qt << 6;

        {   // Q tile transposed: qT[f][j] = q[qbase+j][f]
            float4 qv = *(const float4*)&qbh[(size_t)(qbase + ldj) * 512 + lf4];
            qT[lf4 + 0][ldj] = qv.x; qT[lf4 + 1][ldj] = qv.y;
            qT[lf4 + 2][ldj] = qv.z; qT[lf4 + 3][ldj] = qv.w;
        }

        f32x4 oacc[4];
#pragma unroll
        for (int n = 0; n < 4; ++n) oacc[n] = (f32x4){0.f, 0.f, 0.f, 0.f};
        float zrow[4] = {0.f, 0.f, 0.f, 0.f};

        for (int kt = 0; kt <= qt; ++kt) {
            __syncthreads();   // prev phase2 reads (P, vs) done; covers qT at kt=0
            {
                float4 kv = *(const float4*)&kbh[(size_t)((kt << 6) + ldj) * 512 + lf4];
                kT[lf4 + 0][ldj] = kv.x; kT[lf4 + 1][ldj] = kv.y;
                kT[lf4 + 2][ldj] = kv.z; kT[lf4 + 3][ldj] = kv.w;
                // stage V^T tile: vs[d][j] = vT[d][kt*64 + j]
                const size_t vgo = (size_t)vd * 2048 + (kt << 6) + vc16;
                *(ushort8*)&vs[vd][vc16]     = *(const ushort8*)&vbh[vgo];
                *(ushort8*)&vs[vd][vc16 + 8] = *(const ushort8*)&vbh[vgo + 8];
            }
            __syncthreads();

            // phase 1 (VALU fp32): s = (q.k)^2, causal mask, z accum, P (bf16)
            float sa[4][4];
#pragma unroll
            for (int i = 0; i < 4; ++i)
#pragma unroll
                for (int j = 0; j < 4; ++j) sa[i][j] = 0.f;
#pragma unroll
            for (int f = 0; f < 16; ++f) {
                float4 a4 = *(const float4*)&qT[f][tr4];
                float4 b4 = *(const float4*)&kT[f][tc4];
                float av[4] = {a4.x, a4.y, a4.z, a4.w};
                float bv[4] = {b4.x, b4.y, b4.z, b4.w};
#pragma unroll
                for (int i = 0; i < 4; ++i)
#pragma unroll
                    for (int j = 0; j < 4; ++j)
                        sa[i][j] = fmaf(av[i], bv[j], sa[i][j]);
            }
#pragma unroll
            for (int i = 0; i < 4; ++i) {
                const int row = qbase + tr4 + i;
                ushort4v pv;
#pragma unroll
                for (int j = 0; j < 4; ++j) {
                    const int col = (kt << 6) + tc4 + j;
                    const float d = sa[i][j];
                    const float s2 = (col <= row) ? d * d : 0.f;
                    zrow[i] += s2;
                    pv[j] = f2b(s2);
                }
                *(ushort4v*)&P[tr4 + i][tc4] = pv;   // contiguous 8B, conflict-free
            }
            __syncthreads();   // P visible (wave-local in fact; keep safe)

            // phase 2 (MFMA): O strip [16*wid .. +16) x 64  +=  P_strip @ V
            {
                bf16x8 a0 = *(const bf16x8*)&P[16 * wid + fr][fg * 8];
                bf16x8 a1 = *(const bf16x8*)&P[16 * wid + fr][32 + fg * 8];
#pragma unroll
                for (int nt = 0; nt < 4; ++nt) {
                    bf16x8 b0 = *(const bf16x8*)&vs[nt * 16 + fr][fg * 8];
                    bf16x8 b1 = *(const bf16x8*)&vs[nt * 16 + fr][32 + fg * 8];
                    oacc[nt] = __builtin_amdgcn_mfma_f32_16x16x32_bf16(a0, b0, oacc[nt], 0, 0, 0);
                    oacc[nt] = __builtin_amdgcn_mfma_f32_16x16x32_bf16(a1, b1, oacc[nt], 0, 0, 0);
                }
            }
        }

        // z reduce
        __syncthreads();
#pragma unroll
        for (int i = 0; i < 4; ++i) zp[tr4 + i][t & 15] = zrow[i];
        __syncthreads();
        if (t < 64) {
            float s = 1e-5f;
#pragma unroll
            for (int c = 0; c < 16; ++c) s += zp[t][c];
            zf[t] = 1.f / s;
        }
        __syncthreads();

        // epilogue: C-layout col=lane&15, row=(lane>>4)*4+reg within 16-row strip
#pragma unroll
        for (int reg = 0; reg < 4; ++reg) {
            const int trow = 16 * wid + fg * 4 + reg;          // row within tile
            const float r = zf[trow];
            const size_t gro = (size_t)(qbase + trow) * 1024;
#pragma unroll
            for (int nt = 0; nt < 4; ++nt)
                obh[gro + nt * 16 + fr] = f2b(oacc[nt][reg] * r);
        }
        __syncthreads();   // before next pass overwrites qT / P / vs
    }
}

extern "C" void kernel_launch(void* const* d_in, const int* in_sizes, int n_in,
                              void* d_out, int out_size, void* d_ws, size_t ws_size,
                              hipStream_t stream) {
    const float* x     = (const float*)d_in[0];
    const float* Wq    = (const float*)d_in[1];
    const float* Wk    = (const float*)d_in[2];
    const float* Wv    = (const float*)d_in[3];
    const float* Wo    = (const float*)d_in[4];
    const float* gamma = (const float*)d_in[5];
    const float* beta  = (const float*)d_in[6];
    float* out = (float*)d_out;
    (void)in_sizes; (void)n_in; (void)out_size; (void)ws_size;

    char* w = (char*)d_ws;
    float*          qk_raw = (float*)w;                                   // 8 MB
    unsigned short* vTb    = (unsigned short*)(w + (8u  << 20));          // 8 MB, [bh][64][2048]
    unsigned short* ob     = (unsigned short*)(w + (16u << 20));          // 8 MB
    unsigned short* xh     = (unsigned short*)(w + (24u << 20));          // 8 MB
    unsigned short* xl     = (unsigned short*)(w + (32u << 20));          // 8 MB
    unsigned short* wqkh   = (unsigned short*)(w + (40u << 20));          // 1 MB
    unsigned short* wqkl   = (unsigned short*)(w + (41u << 20));          // 1 MB
    unsigned short* wvb    = (unsigned short*)(w + (42u << 20));          // 2 MB
    unsigned short* wob    = (unsigned short*)(w + (44u << 20));          // 2 MB

    cast_split<<<2048, 256, 0, stream>>>(x,  xh, xl, 4096 * 1024);
    cast_split<<<128,  256, 0, stream>>>(Wq, wqkh, wqkl, 256 * 1024);
    cast_split<<<128,  256, 0, stream>>>(Wk, wqkh + 256 * 1024, wqkl + 256 * 1024, 256 * 1024);
    cast_bf16 <<<512,  256, 0, stream>>>(Wv, wvb, 1024 * 1024);
    cast_bf16 <<<512,  256, 0, stream>>>(Wo, wob, 1024 * 1024);

    // qk projection (split-bf16, ~fp32): [4096][512] f32
    gemm_split<<<dim3(32, 8), 256, 0, stream>>>(xh, xl, wqkh, wqkl, qk_raw, 4096, 512, 1024);
    // v projection -> transposed bf16 vT[bh][d][l]
    gemm_mfma<128, 2><<<dim3(32, 8), 256, 0, stream>>>(xh, wvb, vTb, 4096, 1024, 1024);
    // feature map in-place
    ln_featuremap<<<512, 256, 0, stream>>>(qk_raw, gamma, beta);
    // attention -> bf16 ob (b, l, h*64+d)
    rebased_attn<<<dim3(16, 32), 256, 0, stream>>>(qk_raw, vTb, ob);
    // output projection -> f32 out
    gemm_mfma<128, 0><<<dim3(32, 8), 256, 0, stream>>>(ob, wob, out, 4096, 1024, 1024);
}

// Round 6
// 149.422 us; speedup vs baseline: 4.9077x; 1.1184x over previous
//
#include <hip/hip_runtime.h>
#include <cstddef>
#include <cstdint>

// ReBased linear attention, round 6: attention fully on MFMA.
// Phase 1 (QK^T) via hi|lo split-bf16 packed into one K=32 MFMA pair:
//   MFMA1: A=[kh|kl], B=[qh|qh] -> (kh+kl)·qh ; MFMA2: A=[kh|0], B=[ql|ql] -> kh·ql
// ln_featuremap emits q/k as [bh][l][32] = [hi16|lo16] bf16 rows.
// P[q][k] is wave-private (wave computes S^T for its own q-strip) -> no mid barrier.
// All staging via global_load_lds into [fgroup][row][8] sub-tiled LDS.

typedef __attribute__((ext_vector_type(8)))  __bf16 bf16x8;
typedef __attribute__((ext_vector_type(4)))  __bf16 bf16x4;
typedef __attribute__((ext_vector_type(4)))  float  f32x4;
typedef __attribute__((ext_vector_type(8)))  unsigned short ushort8;
typedef __attribute__((ext_vector_type(4)))  unsigned short ushort4v;

__device__ __forceinline__ unsigned short f2b(float f) {
    union { float f; unsigned u; } v; v.f = f;
    unsigned r = v.u + 0x7FFFu + ((v.u >> 16) & 1u);   // RNE
    return (unsigned short)(r >> 16);
}
__device__ __forceinline__ float b2f(unsigned short b) {
    union { unsigned u; float f; } v; v.u = ((unsigned)b) << 16;
    return v.f;
}

typedef const __attribute__((address_space(1))) void* gas_ptr;
typedef __attribute__((address_space(3))) void* las_ptr;

__device__ __forceinline__ void gload_lds16(const unsigned short* g, unsigned short* l) {
    // 16B/lane; LDS dest = wave-uniform base + lane*16
    __builtin_amdgcn_global_load_lds((gas_ptr)g, (las_ptr)l, 16, 0, 0);
}

// ---------------- bf16 MFMA GEMM: C[M][N] = A[M][K] @ W[N][K]^T ----------------
// OUTMODE: 0 = f32 row-major, 1 = bf16 row-major, 2 = bf16 transposed vT scatter
template <int BN, int OUTMODE>
__global__ __launch_bounds__(256) void gemm_mfma(const unsigned short* __restrict__ A,
                                                 const unsigned short* __restrict__ W,
                                                 void* __restrict__ Cout,
                                                 int M, int N, int K) {
    constexpr int BM = 128, BK = 64;
    constexpr int NF = BN / 32;
    __shared__ __align__(16) unsigned short As[BM * BK];
    __shared__ __align__(16) unsigned short Bs[BN * BK];

    const int t = threadIdx.x;
    const int wid = t >> 6, lane = t & 63;
    const int m0 = blockIdx.x * BM, n0 = blockIdx.y * BN;
    const int wrow = (wid >> 1) * 64;
    const int wcol = (wid & 1) * (BN / 2);
    const int lr = lane & 15, lk = (lane >> 4) * 8;

    f32x4 acc[4][NF];
#pragma unroll
    for (int m = 0; m < 4; ++m)
#pragma unroll
        for (int n = 0; n < NF; ++n) acc[m][n] = (f32x4){0.f, 0.f, 0.f, 0.f};

    const unsigned short* Ag = A + (size_t)m0 * K;
    const unsigned short* Wg = W + (size_t)n0 * K;

    for (int k0 = 0; k0 < K; k0 += BK) {
        __syncthreads();
#pragma unroll
        for (int i = 0; i < BM / 32; ++i) {
            const int e = (i * 256 + wid * 64 + lane) * 8;
            gload_lds16(Ag + (size_t)(e >> 6) * K + k0 + (e & 63),
                        As + (size_t)(i * 256 + wid * 64) * 8);
        }
#pragma unroll
        for (int i = 0; i < BN / 32; ++i) {
            const int e = (i * 256 + wid * 64 + lane) * 8;
            gload_lds16(Wg + (size_t)(e >> 6) * K + k0 + (e & 63),
                        Bs + (size_t)(i * 256 + wid * 64) * 8);
        }
        __syncthreads();

#pragma unroll
        for (int kk = 0; kk < BK; kk += 32) {
            bf16x8 af[4], bf[NF];
#pragma unroll
            for (int m = 0; m < 4; ++m)
                af[m] = *(const bf16x8*)&As[(wrow + m * 16 + lr) * BK + kk + lk];
#pragma unroll
            for (int n = 0; n < NF; ++n)
                bf[n] = *(const bf16x8*)&Bs[(wcol + n * 16 + lr) * BK + kk + lk];
#pragma unroll
            for (int m = 0; m < 4; ++m)
#pragma unroll
                for (int n = 0; n < NF; ++n)
                    acc[m][n] = __builtin_amdgcn_mfma_f32_16x16x32_bf16(af[m], bf[n], acc[m][n], 0, 0, 0);
        }
    }

    const int orow0 = m0 + wrow + (lane >> 4) * 4;
    const int ocol0 = n0 + wcol + lr;
#pragma unroll
    for (int m = 0; m < 4; ++m)
#pragma unroll
        for (int n = 0; n < NF; ++n) {
            if (OUTMODE == 2) {
                const int nc = ocol0 + n * 16;
                const int mrow = orow0 + m * 16;
                unsigned short* dst = (unsigned short*)Cout
                    + (size_t)((mrow >> 11) * 16 + (nc >> 6)) * (64 * 2048)
                    + (size_t)(nc & 63) * 2048 + (mrow & 2047);
                ushort4v pv;
#pragma unroll
                for (int i = 0; i < 4; ++i) pv[i] = f2b(acc[m][n][i]);
                *(ushort4v*)dst = pv;
            } else {
#pragma unroll
                for (int i = 0; i < 4; ++i) {
                    const size_t idx = (size_t)(orow0 + m * 16 + i) * N + ocol0 + n * 16;
                    if (OUTMODE == 1) ((unsigned short*)Cout)[idx] = f2b(acc[m][n][i]);
                    else              ((float*)Cout)[idx] = acc[m][n][i];
                }
            }
        }
}

// ------------- split-bf16 GEMM (qk projection): ~fp32 via hi/lo -------------
__global__ __launch_bounds__(256) void gemm_split(const unsigned short* __restrict__ Ah,
                                                  const unsigned short* __restrict__ Al,
                                                  const unsigned short* __restrict__ Wh,
                                                  const unsigned short* __restrict__ Wl,
                                                  float* __restrict__ C,
                                                  int M, int N, int K) {
    constexpr int BM = 128, BN = 64, BK = 64;
    constexpr int NF = BN / 32;
    __shared__ __align__(16) unsigned short Ahs[BM * BK];
    __shared__ __align__(16) unsigned short Als[BM * BK];
    __shared__ __align__(16) unsigned short Bhs[BN * BK];
    __shared__ __align__(16) unsigned short Bls[BN * BK];

    const int t = threadIdx.x;
    const int wid = t >> 6, lane = t & 63;
    const int m0 = blockIdx.x * BM, n0 = blockIdx.y * BN;
    const int wrow = (wid >> 1) * 64;
    const int wcol = (wid & 1) * (BN / 2);
    const int lr = lane & 15, lk = (lane >> 4) * 8;

    f32x4 acc[4][NF];
#pragma unroll
    for (int m = 0; m < 4; ++m)
#pragma unroll
        for (int n = 0; n < NF; ++n) acc[m][n] = (f32x4){0.f, 0.f, 0.f, 0.f};

    const unsigned short* Ahg = Ah + (size_t)m0 * K;
    const unsigned short* Alg = Al + (size_t)m0 * K;
    const unsigned short* Whg = Wh + (size_t)n0 * K;
    const unsigned short* Wlg = Wl + (size_t)n0 * K;

    for (int k0 = 0; k0 < K; k0 += BK) {
        __syncthreads();
#pragma unroll
        for (int i = 0; i < BM / 32; ++i) {
            const int e = (i * 256 + wid * 64 + lane) * 8;
            const size_t go = (size_t)(e >> 6) * K + k0 + (e & 63);
            const size_t lo = (size_t)(i * 256 + wid * 64) * 8;
            gload_lds16(Ahg + go, Ahs + lo);
            gload_lds16(Alg + go, Als + lo);
        }
#pragma unroll
        for (int i = 0; i < BN / 32; ++i) {
            const int e = (i * 256 + wid * 64 + lane) * 8;
            const size_t go = (size_t)(e >> 6) * K + k0 + (e & 63);
            const size_t lo = (size_t)(i * 256 + wid * 64) * 8;
            gload_lds16(Whg + go, Bhs + lo);
            gload_lds16(Wlg + go, Bls + lo);
        }
        __syncthreads();

#pragma unroll
        for (int kk = 0; kk < BK; kk += 32) {
            bf16x8 afh[4], afl[4], bfh[NF], bfl[NF];
#pragma unroll
            for (int m = 0; m < 4; ++m) {
                afh[m] = *(const bf16x8*)&Ahs[(wrow + m * 16 + lr) * BK + kk + lk];
                afl[m] = *(const bf16x8*)&Als[(wrow + m * 16 + lr) * BK + kk + lk];
            }
#pragma unroll
            for (int n = 0; n < NF; ++n) {
                bfh[n] = *(const bf16x8*)&Bhs[(wcol + n * 16 + lr) * BK + kk + lk];
                bfl[n] = *(const bf16x8*)&Bls[(wcol + n * 16 + lr) * BK + kk + lk];
            }
#pragma unroll
            for (int m = 0; m < 4; ++m)
#pragma unroll
                for (int n = 0; n < NF; ++n) {
                    acc[m][n] = __builtin_amdgcn_mfma_f32_16x16x32_bf16(afh[m], bfh[n], acc[m][n], 0, 0, 0);
                    acc[m][n] = __builtin_amdgcn_mfma_f32_16x16x32_bf16(afh[m], bfl[n], acc[m][n], 0, 0, 0);
                    acc[m][n] = __builtin_amdgcn_mfma_f32_16x16x32_bf16(afl[m], bfh[n], acc[m][n], 0, 0, 0);
                }
        }
    }

    const int orow0 = m0 + wrow + (lane >> 4) * 4;
    const int ocol0 = n0 + wcol + lr;
#pragma unroll
    for (int m = 0; m < 4; ++m)
#pragma unroll
        for (int n = 0; n < NF; ++n)
#pragma unroll
            for (int i = 0; i < 4; ++i)
                C[(size_t)(orow0 + m * 16 + i) * N + ocol0 + n * 16] = acc[m][n][i];
}

// ---------------- f32 -> bf16 casts ----------------
__global__ __launch_bounds__(256) void cast_bf16(const float* __restrict__ in,
                                                 unsigned short* __restrict__ out, int n) {
    const int i = (blockIdx.x * 256 + threadIdx.x) * 8;
    if (i >= n) return;
    float4 a = *(const float4*)(in + i);
    float4 b = *(const float4*)(in + i + 4);
    ushort8 o;
    o[0] = f2b(a.x); o[1] = f2b(a.y); o[2] = f2b(a.z); o[3] = f2b(a.w);
    o[4] = f2b(b.x); o[5] = f2b(b.y); o[6] = f2b(b.z); o[7] = f2b(b.w);
    *(ushort8*)(out + i) = o;
}

__global__ __launch_bounds__(256) void cast_split(const float* __restrict__ in,
                                                  unsigned short* __restrict__ hi,
                                                  unsigned short* __restrict__ lo, int n) {
    const int i = (blockIdx.x * 256 + threadIdx.x) * 8;
    if (i >= n) return;
    float4 a = *(const float4*)(in + i);
    float4 b = *(const float4*)(in + i + 4);
    float xv[8] = {a.x, a.y, a.z, a.w, b.x, b.y, b.z, b.w};
    ushort8 oh, ol;
#pragma unroll
    for (int e = 0; e < 8; ++e) {
        const unsigned short h = f2b(xv[e]);
        oh[e] = h;
        ol[e] = f2b(xv[e] - b2f(h));
    }
    *(ushort8*)(hi + i) = oh;
    *(ushort8*)(lo + i) = ol;
}

// ------- feature map: qk_raw f32 -> q/k split hi|lo bf16 [bh][l][32] -------
__global__ __launch_bounds__(256) void ln_featuremap(const float* __restrict__ qk,
                                                     const float* __restrict__ gamma,
                                                     const float* __restrict__ beta,
                                                     unsigned short* __restrict__ qhl,
                                                     unsigned short* __restrict__ khl) {
    const int gid = blockIdx.x * 256 + threadIdx.x;   // (b*2048+l)*32 + idx
    const int idx = gid & 31;
    const int m = gid >> 5;                            // b*2048 + l
    const int b = m >> 11, l = m & 2047;
    const int h = idx & 15;
    const float scale = (idx < 16) ? 0.25f : 1.0f;
    const float* p = qk + (size_t)gid * 16;

    float xv[16];
    float4 v0 = *(const float4*)(p + 0);
    float4 v1 = *(const float4*)(p + 4);
    float4 v2 = *(const float4*)(p + 8);
    float4 v3 = *(const float4*)(p + 12);
    xv[0]=v0.x; xv[1]=v0.y; xv[2]=v0.z; xv[3]=v0.w;
    xv[4]=v1.x; xv[5]=v1.y; xv[6]=v1.z; xv[7]=v1.w;
    xv[8]=v2.x; xv[9]=v2.y; xv[10]=v2.z; xv[11]=v2.w;
    xv[12]=v3.x; xv[13]=v3.y; xv[14]=v3.z; xv[15]=v3.w;

    float mu = 0.f;
#pragma unroll
    for (int f = 0; f < 16; ++f) mu += xv[f];
    mu *= 0.0625f;
    float var = 0.f;
#pragma unroll
    for (int f = 0; f < 16; ++f) { float d = xv[f] - mu; var = fmaf(d, d, var); }
    var *= 0.0625f;
    const float rs = rsqrtf(var + 1e-5f);

    ushort8 hi0, hi1, lo0, lo1;
#pragma unroll
    for (int f = 0; f < 16; ++f) {
        const float v = ((xv[f] - mu) * rs * gamma[f] + beta[f]) * scale;
        const unsigned short hb = f2b(v);
        const unsigned short lb = f2b(v - b2f(hb));
        if (f < 8) { hi0[f] = hb; lo0[f] = lb; }
        else       { hi1[f - 8] = hb; lo1[f - 8] = lb; }
    }
    unsigned short* dst = ((idx < 16) ? qhl : khl)
        + ((size_t)(b * 16 + h) * 2048 + l) * 32;
    *(ushort8*)(dst + 0)  = hi0;
    *(ushort8*)(dst + 8)  = hi1;
    *(ushort8*)(dst + 16) = lo0;
    *(ushort8*)(dst + 24) = lo1;
}

// ------- causal (q.k)^2 attention: full MFMA -------
// grid (16, 32). qhl/khl: [bh][l][32]=[hi16|lo16]; vT: [bh][64 d][2048 l].
__global__ __launch_bounds__(256) void rebased_attn(const unsigned short* __restrict__ qhl_g,
                                                    const unsigned short* __restrict__ khl_g,
                                                    const unsigned short* __restrict__ vT,
                                                    unsigned short* __restrict__ o) {
    const int bh = blockIdx.y;
    const int bb = bh >> 4;
    const int t = threadIdx.x;
    const int wid = t >> 6, lane = t & 63;
    const int fr = lane & 15;           // frag row/col within 16
    const int fg = lane >> 4;           // frag k-octet group 0..3

    // [fgroup][row 64][8 shorts] sub-tiled LDS (conflict-minimal frag reads)
    __shared__ __align__(16) unsigned short qhl[4 * 64 * 8];
    __shared__ __align__(16) unsigned short khl[4 * 64 * 8];
    __shared__ __align__(16) unsigned short vsl[8 * 64 * 8];
    __shared__ __align__(16) __bf16 P[64][72];   // wave-private q-strips

    const unsigned short* qg  = qhl_g + (size_t)bh * 2048 * 32;
    const unsigned short* kg  = khl_g + (size_t)bh * 2048 * 32;
    const unsigned short* vbh = vT + (size_t)bh * 64 * 2048;
    unsigned short*       obh = o  + (size_t)bb * 2048 * 1024 + (bh & 15) * 64;

    const bf16x8 z8 = {(__bf16)0.f,(__bf16)0.f,(__bf16)0.f,(__bf16)0.f,
                       (__bf16)0.f,(__bf16)0.f,(__bf16)0.f,(__bf16)0.f};
    const f32x4 zc = (f32x4){0.f, 0.f, 0.f, 0.f};

    for (int pass = 0; pass < 2; ++pass) {
        const int qt = pass ? (31 - (int)blockIdx.x) : (int)blockIdx.x;
        const int qbase = qt << 6;

        __syncthreads();   // prev pass done with qhl
        // stage q tile: wave w stages feature-octet w of rows qbase..+63
        gload_lds16(qg + (size_t)(qbase + lane) * 32 + wid * 8, qhl + wid * 512);
        __syncthreads();

        // hoist B-fragments (constant over kt): [qh|qh] and [ql|ql]
        const bf16x8 bq1 = *(const bf16x8*)&qhl[(((fg & 1)    ) * 64 + 16 * wid + fr) * 8];
        const bf16x8 bq2 = *(const bf16x8*)&qhl[(((fg & 1) + 2) * 64 + 16 * wid + fr) * 8];

        f32x4 oacc[4];
#pragma unroll
        for (int n = 0; n < 4; ++n) oacc[n] = zc;
        float zlane = 0.f;

        for (int kt = 0; kt <= qt; ++kt) {
            __syncthreads();   // prev step's khl/vsl reads done
            // stage K tile (1 inst/wave) and V^T tile (2 insts/wave)
            gload_lds16(kg + (size_t)((kt << 6) + lane) * 32 + wid * 8, khl + wid * 512);
            gload_lds16(vbh + (size_t)lane * 2048 + (kt << 6) + (2 * wid) * 8,
                        vsl + (2 * wid) * 512);
            gload_lds16(vbh + (size_t)lane * 2048 + (kt << 6) + (2 * wid + 1) * 8,
                        vsl + (2 * wid + 1) * 512);
            __syncthreads();   // staging complete (vmcnt drained)

            // phase 1: S^T strip = K(all 64) x Q(wave's 16), hi/lo MFMA pair
#pragma unroll
            for (int nrow = 0; nrow < 4; ++nrow) {
                const bf16x8 ak  = *(const bf16x8*)&khl[(fg * 64 + nrow * 16 + fr) * 8];
                const bf16x8 ak2 = (fg < 2) ? ak : z8;           // [kh|0]
                f32x4 s = __builtin_amdgcn_mfma_f32_16x16x32_bf16(ak2, bq2, zc, 0, 0, 0);
                s = __builtin_amdgcn_mfma_f32_16x16x32_bf16(ak, bq1, s, 0, 0, 0);

                // lane holds S^T[k = nrow*16+fg*4+reg][q = 16*wid+fr]
                float s2[4];
                if (kt == qt) {
                    const int qr = 16 * wid + fr;
                    const int kc = nrow * 16 + fg * 4;
#pragma unroll
                    for (int reg = 0; reg < 4; ++reg) {
                        float x = s[reg];
                        float y = x * x;
                        s2[reg] = (kc + reg <= qr) ? y : 0.f;
                        zlane += s2[reg];
                    }
                } else {
#pragma unroll
                    for (int reg = 0; reg < 4; ++reg) {
                        float x = s[reg];
                        s2[reg] = x * x;
                        zlane += s2[reg];
                    }
                }
                bf16x4 pv = {(__bf16)s2[0], (__bf16)s2[1], (__bf16)s2[2], (__bf16)s2[3]};
                *(bf16x4*)&P[16 * wid + fr][nrow * 16 + fg * 4] = pv;   // wave-private row
            }

            // phase 2: O strip += P_strip @ V  (same-wave P, no barrier needed)
            const bf16x8 a0 = *(const bf16x8*)&P[16 * wid + fr][fg * 8];
            const bf16x8 a1 = *(const bf16x8*)&P[16 * wid + fr][32 + fg * 8];
#pragma unroll
            for (int nt = 0; nt < 4; ++nt) {
                const bf16x8 b0 = *(const bf16x8*)&vsl[((fg    ) * 64 + nt * 16 + fr) * 8];
                const bf16x8 b1 = *(const bf16x8*)&vsl[((fg + 4) * 64 + nt * 16 + fr) * 8];
                oacc[nt] = __builtin_amdgcn_mfma_f32_16x16x32_bf16(a0, b0, oacc[nt], 0, 0, 0);
                oacc[nt] = __builtin_amdgcn_mfma_f32_16x16x32_bf16(a1, b1, oacc[nt], 0, 0, 0);
            }
        }

        // z: lane groups share q=16*wid+fr -> butterfly over lane^16, lane^32
        float z = zlane;
        z += __shfl_xor(z, 16);
        z += __shfl_xor(z, 32);
        const float zinv = 1.f / (z + 1e-5f);

        // epilogue: oacc D-layout row = fg*4+reg (q), col = fr (d within nt)
#pragma unroll
        for (int reg = 0; reg < 4; ++reg) {
            const float r = __shfl(zinv, fg * 4 + reg);   // zinv held at lane (q&15)
            const size_t gro = (size_t)(qbase + 16 * wid + fg * 4 + reg) * 1024;
#pragma unroll
            for (int nt = 0; nt < 4; ++nt)
                obh[gro + nt * 16 + fr] = f2b(oacc[nt][reg] * r);
        }
    }
}

extern "C" void kernel_launch(void* const* d_in, const int* in_sizes, int n_in,
                              void* d_out, int out_size, void* d_ws, size_t ws_size,
                              hipStream_t stream) {
    const float* x     = (const float*)d_in[0];
    const float* Wq    = (const float*)d_in[1];
    const float* Wk    = (const float*)d_in[2];
    const float* Wv    = (const float*)d_in[3];
    const float* Wo    = (const float*)d_in[4];
    const float* gamma = (const float*)d_in[5];
    const float* beta  = (const float*)d_in[6];
    float* out = (float*)d_out;
    (void)in_sizes; (void)n_in; (void)out_size; (void)ws_size;

    char* w = (char*)d_ws;
    float*          qk_raw = (float*)w;                                   // 8 MB @ 0
    unsigned short* vTb    = (unsigned short*)(w + (8u  << 20));          // 8 MB [bh][64][2048]
    unsigned short* ob     = (unsigned short*)(w + (16u << 20));          // 8 MB
    unsigned short* xh     = (unsigned short*)(w + (24u << 20));          // 8 MB (dead after gemms)
    unsigned short* xl     = (unsigned short*)(w + (32u << 20));          // 8 MB (dead after gemm_split)
    unsigned short* qhl_g  = (unsigned short*)(w + (24u << 20));          // 4 MB (overlays dead xh)
    unsigned short* khl_g  = (unsigned short*)(w + (28u << 20));          // 4 MB (overlays dead xh)
    unsigned short* wqkh   = (unsigned short*)(w + (40u << 20));          // 1 MB
    unsigned short* wqkl   = (unsigned short*)(w + (41u << 20));          // 1 MB
    unsigned short* wvb    = (unsigned short*)(w + (42u << 20));          // 2 MB
    unsigned short* wob    = (unsigned short*)(w + (44u << 20));          // 2 MB

    cast_split<<<2048, 256, 0, stream>>>(x,  xh, xl, 4096 * 1024);
    cast_split<<<128,  256, 0, stream>>>(Wq, wqkh, wqkl, 256 * 1024);
    cast_split<<<128,  256, 0, stream>>>(Wk, wqkh + 256 * 1024, wqkl + 256 * 1024, 256 * 1024);
    cast_bf16 <<<512,  256, 0, stream>>>(Wv, wvb, 1024 * 1024);
    cast_bf16 <<<512,  256, 0, stream>>>(Wo, wob, 1024 * 1024);

    // qk projection (split-bf16, ~fp32): [4096][512] f32
    gemm_split<<<dim3(32, 8), 256, 0, stream>>>(xh, xl, wqkh, wqkl, qk_raw, 4096, 512, 1024);
    // v projection -> transposed bf16 vT[bh][d][l]
    gemm_mfma<128, 2><<<dim3(32, 8), 256, 0, stream>>>(xh, wvb, vTb, 4096, 1024, 1024);
    // feature map -> q/k hi|lo bf16 [bh][l][32] (xh/xl now dead; overlaid)
    ln_featuremap<<<512, 256, 0, stream>>>(qk_raw, gamma, beta, qhl_g, khl_g);
    // attention -> bf16 ob (b, l, h*64+d)
    rebased_attn<<<dim3(16, 32), 256, 0, stream>>>(qhl_g, khl_g, vTb, ob);
    // output projection -> f32 out
    gemm_mfma<128, 0><<<dim3(32, 8), 256, 0, stream>>>(ob, wob, out, 4096, 1024, 1024);
}

// Round 7
// 125.293 us; speedup vs baseline: 5.8529x; 1.1926x over previous
//
#include <hip/hip_runtime.h>
#include <cstddef>
#include <cstdint>

// ReBased linear attention, round 7.
// r6 post-mortem: attn latency-bound (2 barriers/step + full drain before compute;
// MfmaUtil 12%, VALUBusy 23%). Fixes:
//  - attn: double-buffered K/V staging, prefetch-before-compute, one
//    vmcnt(0)+s_barrier per step (T3 minimum 2-phase).
//  - GEMMs: BM=64 tiles -> 512-block grids = 2 blocks/CU (was 1).

typedef __attribute__((ext_vector_type(8)))  __bf16 bf16x8;
typedef __attribute__((ext_vector_type(4)))  __bf16 bf16x4;
typedef __attribute__((ext_vector_type(4)))  float  f32x4;
typedef __attribute__((ext_vector_type(8)))  unsigned short ushort8;
typedef __attribute__((ext_vector_type(4)))  unsigned short ushort4v;

__device__ __forceinline__ unsigned short f2b(float f) {
    union { float f; unsigned u; } v; v.f = f;
    unsigned r = v.u + 0x7FFFu + ((v.u >> 16) & 1u);   // RNE
    return (unsigned short)(r >> 16);
}
__device__ __forceinline__ float b2f(unsigned short b) {
    union { unsigned u; float f; } v; v.u = ((unsigned)b) << 16;
    return v.f;
}

typedef const __attribute__((address_space(1))) void* gas_ptr;
typedef __attribute__((address_space(3))) void* las_ptr;

__device__ __forceinline__ void gload_lds16(const unsigned short* g, unsigned short* l) {
    // 16B/lane; LDS dest = wave-uniform base + lane*16
    __builtin_amdgcn_global_load_lds((gas_ptr)g, (las_ptr)l, 16, 0, 0);
}

// ---------------- bf16 MFMA GEMM: C[M][N] = A[M][K] @ W[N][K]^T ----------------
// 256 threads = 4 waves (2x2). OUTMODE: 0=f32, 1=bf16, 2=bf16 vT scatter.
template <int BM, int BN, int OUTMODE>
__global__ __launch_bounds__(256) void gemm_mfma(const unsigned short* __restrict__ A,
                                                 const unsigned short* __restrict__ W,
                                                 void* __restrict__ Cout,
                                                 int M, int N, int K) {
    constexpr int BK = 64;
    constexpr int MF = BM / 32;
    constexpr int NF = BN / 32;
    __shared__ __align__(16) unsigned short As[BM * BK];
    __shared__ __align__(16) unsigned short Bs[BN * BK];

    const int t = threadIdx.x;
    const int wid = t >> 6, lane = t & 63;
    const int m0 = blockIdx.x * BM, n0 = blockIdx.y * BN;
    const int wrow = (wid >> 1) * (BM / 2);
    const int wcol = (wid & 1) * (BN / 2);
    const int lr = lane & 15, lk = (lane >> 4) * 8;

    f32x4 acc[MF][NF];
#pragma unroll
    for (int m = 0; m < MF; ++m)
#pragma unroll
        for (int n = 0; n < NF; ++n) acc[m][n] = (f32x4){0.f, 0.f, 0.f, 0.f};

    const unsigned short* Ag = A + (size_t)m0 * K;
    const unsigned short* Wg = W + (size_t)n0 * K;

    for (int k0 = 0; k0 < K; k0 += BK) {
        __syncthreads();
#pragma unroll
        for (int i = 0; i < BM / 32; ++i) {
            const int e = (i * 256 + wid * 64 + lane) * 8;
            gload_lds16(Ag + (size_t)(e >> 6) * K + k0 + (e & 63),
                        As + (size_t)(i * 256 + wid * 64) * 8);
        }
#pragma unroll
        for (int i = 0; i < BN / 32; ++i) {
            const int e = (i * 256 + wid * 64 + lane) * 8;
            gload_lds16(Wg + (size_t)(e >> 6) * K + k0 + (e & 63),
                        Bs + (size_t)(i * 256 + wid * 64) * 8);
        }
        __syncthreads();

#pragma unroll
        for (int kk = 0; kk < BK; kk += 32) {
            bf16x8 af[MF], bf[NF];
#pragma unroll
            for (int m = 0; m < MF; ++m)
                af[m] = *(const bf16x8*)&As[(wrow + m * 16 + lr) * BK + kk + lk];
#pragma unroll
            for (int n = 0; n < NF; ++n)
                bf[n] = *(const bf16x8*)&Bs[(wcol + n * 16 + lr) * BK + kk + lk];
#pragma unroll
            for (int m = 0; m < MF; ++m)
#pragma unroll
                for (int n = 0; n < NF; ++n)
                    acc[m][n] = __builtin_amdgcn_mfma_f32_16x16x32_bf16(af[m], bf[n], acc[m][n], 0, 0, 0);
        }
    }

    const int orow0 = m0 + wrow + (lane >> 4) * 4;
    const int ocol0 = n0 + wcol + lr;
#pragma unroll
    for (int m = 0; m < MF; ++m)
#pragma unroll
        for (int n = 0; n < NF; ++n) {
            if (OUTMODE == 2) {
                const int nc = ocol0 + n * 16;
                const int mrow = orow0 + m * 16;
                unsigned short* dst = (unsigned short*)Cout
                    + (size_t)((mrow >> 11) * 16 + (nc >> 6)) * (64 * 2048)
                    + (size_t)(nc & 63) * 2048 + (mrow & 2047);
                ushort4v pv;
#pragma unroll
                for (int i = 0; i < 4; ++i) pv[i] = f2b(acc[m][n][i]);
                *(ushort4v*)dst = pv;
            } else {
#pragma unroll
                for (int i = 0; i < 4; ++i) {
                    const size_t idx = (size_t)(orow0 + m * 16 + i) * N + ocol0 + n * 16;
                    if (OUTMODE == 1) ((unsigned short*)Cout)[idx] = f2b(acc[m][n][i]);
                    else              ((float*)Cout)[idx] = acc[m][n][i];
                }
            }
        }
}

// ------------- split-bf16 GEMM (qk projection): ~fp32 via hi/lo, BM=64 -------------
__global__ __launch_bounds__(256) void gemm_split(const unsigned short* __restrict__ Ah,
                                                  const unsigned short* __restrict__ Al,
                                                  const unsigned short* __restrict__ Wh,
                                                  const unsigned short* __restrict__ Wl,
                                                  float* __restrict__ C,
                                                  int M, int N, int K) {
    constexpr int BM = 64, BN = 64, BK = 64;
    constexpr int MF = 2, NF = 2;
    __shared__ __align__(16) unsigned short Ahs[BM * BK];
    __shared__ __align__(16) unsigned short Als[BM * BK];
    __shared__ __align__(16) unsigned short Bhs[BN * BK];
    __shared__ __align__(16) unsigned short Bls[BN * BK];

    const int t = threadIdx.x;
    const int wid = t >> 6, lane = t & 63;
    const int m0 = blockIdx.x * BM, n0 = blockIdx.y * BN;
    const int wrow = (wid >> 1) * 32;
    const int wcol = (wid & 1) * 32;
    const int lr = lane & 15, lk = (lane >> 4) * 8;

    f32x4 acc[MF][NF];
#pragma unroll
    for (int m = 0; m < MF; ++m)
#pragma unroll
        for (int n = 0; n < NF; ++n) acc[m][n] = (f32x4){0.f, 0.f, 0.f, 0.f};

    const unsigned short* Ahg = Ah + (size_t)m0 * K;
    const unsigned short* Alg = Al + (size_t)m0 * K;
    const unsigned short* Whg = Wh + (size_t)n0 * K;
    const unsigned short* Wlg = Wl + (size_t)n0 * K;

    for (int k0 = 0; k0 < K; k0 += BK) {
        __syncthreads();
#pragma unroll
        for (int i = 0; i < BM / 32; ++i) {
            const int e = (i * 256 + wid * 64 + lane) * 8;
            const size_t go = (size_t)(e >> 6) * K + k0 + (e & 63);
            const size_t lo = (size_t)(i * 256 + wid * 64) * 8;
            gload_lds16(Ahg + go, Ahs + lo);
            gload_lds16(Alg + go, Als + lo);
            gload_lds16(Whg + go, Bhs + lo);
            gload_lds16(Wlg + go, Bls + lo);
        }
        __syncthreads();

#pragma unroll
        for (int kk = 0; kk < BK; kk += 32) {
            bf16x8 afh[MF], afl[MF], bfh[NF], bfl[NF];
#pragma unroll
            for (int m = 0; m < MF; ++m) {
                afh[m] = *(const bf16x8*)&Ahs[(wrow + m * 16 + lr) * BK + kk + lk];
                afl[m] = *(const bf16x8*)&Als[(wrow + m * 16 + lr) * BK + kk + lk];
            }
#pragma unroll
            for (int n = 0; n < NF; ++n) {
                bfh[n] = *(const bf16x8*)&Bhs[(wcol + n * 16 + lr) * BK + kk + lk];
                bfl[n] = *(const bf16x8*)&Bls[(wcol + n * 16 + lr) * BK + kk + lk];
            }
#pragma unroll
            for (int m = 0; m < MF; ++m)
#pragma unroll
                for (int n = 0; n < NF; ++n) {
                    acc[m][n] = __builtin_amdgcn_mfma_f32_16x16x32_bf16(afh[m], bfh[n], acc[m][n], 0, 0, 0);
                    acc[m][n] = __builtin_amdgcn_mfma_f32_16x16x32_bf16(afh[m], bfl[n], acc[m][n], 0, 0, 0);
                    acc[m][n] = __builtin_amdgcn_mfma_f32_16x16x32_bf16(afl[m], bfh[n], acc[m][n], 0, 0, 0);
                }
        }
    }

    const int orow0 = m0 + wrow + (lane >> 4) * 4;
    const int ocol0 = n0 + wcol + lr;
#pragma unroll
    for (int m = 0; m < MF; ++m)
#pragma unroll
        for (int n = 0; n < NF; ++n)
#pragma unroll
            for (int i = 0; i < 4; ++i)
                C[(size_t)(orow0 + m * 16 + i) * N + ocol0 + n * 16] = acc[m][n][i];
}

// ---------------- f32 -> bf16 casts ----------------
__global__ __launch_bounds__(256) void cast_bf16(const float* __restrict__ in,
                                                 unsigned short* __restrict__ out, int n) {
    const int i = (blockIdx.x * 256 + threadIdx.x) * 8;
    if (i >= n) return;
    float4 a = *(const float4*)(in + i);
    float4 b = *(const float4*)(in + i + 4);
    ushort8 o;
    o[0] = f2b(a.x); o[1] = f2b(a.y); o[2] = f2b(a.z); o[3] = f2b(a.w);
    o[4] = f2b(b.x); o[5] = f2b(b.y); o[6] = f2b(b.z); o[7] = f2b(b.w);
    *(ushort8*)(out + i) = o;
}

__global__ __launch_bounds__(256) void cast_split(const float* __restrict__ in,
                                                  unsigned short* __restrict__ hi,
                                                  unsigned short* __restrict__ lo, int n) {
    const int i = (blockIdx.x * 256 + threadIdx.x) * 8;
    if (i >= n) return;
    float4 a = *(const float4*)(in + i);
    float4 b = *(const float4*)(in + i + 4);
    float xv[8] = {a.x, a.y, a.z, a.w, b.x, b.y, b.z, b.w};
    ushort8 oh, ol;
#pragma unroll
    for (int e = 0; e < 8; ++e) {
        const unsigned short h = f2b(xv[e]);
        oh[e] = h;
        ol[e] = f2b(xv[e] - b2f(h));
    }
    *(ushort8*)(hi + i) = oh;
    *(ushort8*)(lo + i) = ol;
}

// ------- feature map: qk_raw f32 -> q/k split hi|lo bf16 [bh][l][32] -------
__global__ __launch_bounds__(256) void ln_featuremap(const float* __restrict__ qk,
                                                     const float* __restrict__ gamma,
                                                     const float* __restrict__ beta,
                                                     unsigned short* __restrict__ qhl,
                                                     unsigned short* __restrict__ khl) {
    const int gid = blockIdx.x * 256 + threadIdx.x;
    const int idx = gid & 31;
    const int m = gid >> 5;
    const int b = m >> 11, l = m & 2047;
    const int h = idx & 15;
    const float scale = (idx < 16) ? 0.25f : 1.0f;
    const float* p = qk + (size_t)gid * 16;

    float xv[16];
    float4 v0 = *(const float4*)(p + 0);
    float4 v1 = *(const float4*)(p + 4);
    float4 v2 = *(const float4*)(p + 8);
    float4 v3 = *(const float4*)(p + 12);
    xv[0]=v0.x; xv[1]=v0.y; xv[2]=v0.z; xv[3]=v0.w;
    xv[4]=v1.x; xv[5]=v1.y; xv[6]=v1.z; xv[7]=v1.w;
    xv[8]=v2.x; xv[9]=v2.y; xv[10]=v2.z; xv[11]=v2.w;
    xv[12]=v3.x; xv[13]=v3.y; xv[14]=v3.z; xv[15]=v3.w;

    float mu = 0.f;
#pragma unroll
    for (int f = 0; f < 16; ++f) mu += xv[f];
    mu *= 0.0625f;
    float var = 0.f;
#pragma unroll
    for (int f = 0; f < 16; ++f) { float d = xv[f] - mu; var = fmaf(d, d, var); }
    var *= 0.0625f;
    const float rs = rsqrtf(var + 1e-5f);

    ushort8 hi0, hi1, lo0, lo1;
#pragma unroll
    for (int f = 0; f < 16; ++f) {
        const float v = ((xv[f] - mu) * rs * gamma[f] + beta[f]) * scale;
        const unsigned short hb = f2b(v);
        const unsigned short lb = f2b(v - b2f(hb));
        if (f < 8) { hi0[f] = hb; lo0[f] = lb; }
        else       { hi1[f - 8] = hb; lo1[f - 8] = lb; }
    }
    unsigned short* dst = ((idx < 16) ? qhl : khl)
        + ((size_t)(b * 16 + h) * 2048 + l) * 32;
    *(ushort8*)(dst + 0)  = hi0;
    *(ushort8*)(dst + 8)  = hi1;
    *(ushort8*)(dst + 16) = lo0;
    *(ushort8*)(dst + 24) = lo1;
}

// ------- causal (q.k)^2 attention: full MFMA, double-buffered staging -------
// grid (16, 32). qhl/khl: [bh][l][32]=[hi16|lo16]; vT: [bh][64 d][2048 l].
__global__ __launch_bounds__(256) void rebased_attn(const unsigned short* __restrict__ qhl_g,
                                                    const unsigned short* __restrict__ khl_g,
                                                    const unsigned short* __restrict__ vT,
                                                    unsigned short* __restrict__ o) {
    const int bh = blockIdx.y;
    const int bb = bh >> 4;
    const int t = threadIdx.x;
    const int wid = t >> 6, lane = t & 63;
    const int fr = lane & 15;
    const int fg = lane >> 4;

    __shared__ __align__(16) unsigned short qhl[4 * 64 * 8];
    __shared__ __align__(16) unsigned short khl[2][4 * 64 * 8];
    __shared__ __align__(16) unsigned short vsl[2][8 * 64 * 8];
    __shared__ __align__(16) __bf16 P[64][72];

    const unsigned short* qg  = qhl_g + (size_t)bh * 2048 * 32;
    const unsigned short* kg  = khl_g + (size_t)bh * 2048 * 32;
    const unsigned short* vbh = vT + (size_t)bh * 64 * 2048;
    unsigned short*       obh = o  + (size_t)bb * 2048 * 1024 + (bh & 15) * 64;

    const bf16x8 z8 = {(__bf16)0.f,(__bf16)0.f,(__bf16)0.f,(__bf16)0.f,
                       (__bf16)0.f,(__bf16)0.f,(__bf16)0.f,(__bf16)0.f};
    const f32x4 zc = (f32x4){0.f, 0.f, 0.f, 0.f};

    for (int pass = 0; pass < 2; ++pass) {
        const int qt = pass ? (31 - (int)blockIdx.x) : (int)blockIdx.x;
        const int qbase = qt << 6;

        __syncthreads();   // prev pass fully done with qhl / khl / vsl
        // stage q tile + kt=0 K/V into buf0
        gload_lds16(qg + (size_t)(qbase + lane) * 32 + wid * 8, qhl + wid * 512);
        gload_lds16(kg + (size_t)lane * 32 + wid * 8, &khl[0][wid * 512]);
        gload_lds16(vbh + (size_t)lane * 2048 + (2 * wid) * 8, &vsl[0][(2 * wid) * 512]);
        gload_lds16(vbh + (size_t)lane * 2048 + (2 * wid + 1) * 8, &vsl[0][(2 * wid + 1) * 512]);
        __syncthreads();   // drains vmcnt: q + first tiles ready

        // hoist B-fragments (constant over kt): [qh|qh] and [ql|ql]
        const bf16x8 bq1 = *(const bf16x8*)&qhl[(((fg & 1)    ) * 64 + 16 * wid + fr) * 8];
        const bf16x8 bq2 = *(const bf16x8*)&qhl[(((fg & 1) + 2) * 64 + 16 * wid + fr) * 8];

        f32x4 oacc[4];
#pragma unroll
        for (int n = 0; n < 4; ++n) oacc[n] = zc;
        float zlane = 0.f;

        int cur = 0;
        for (int kt = 0; kt <= qt; ++kt) {
            // prefetch next tile into other buffer (overlaps compute below)
            if (kt < qt) {
                const int nb = cur ^ 1;
                gload_lds16(kg + (size_t)(((kt + 1) << 6) + lane) * 32 + wid * 8,
                            &khl[nb][wid * 512]);
                gload_lds16(vbh + (size_t)lane * 2048 + ((kt + 1) << 6) + (2 * wid) * 8,
                            &vsl[nb][(2 * wid) * 512]);
                gload_lds16(vbh + (size_t)lane * 2048 + ((kt + 1) << 6) + (2 * wid + 1) * 8,
                            &vsl[nb][(2 * wid + 1) * 512]);
            }

            // phase 1: S^T strip = K(all 64) x Q(wave's 16), hi/lo MFMA pair
#pragma unroll
            for (int nrow = 0; nrow < 4; ++nrow) {
                const bf16x8 ak  = *(const bf16x8*)&khl[cur][(fg * 64 + nrow * 16 + fr) * 8];
                const bf16x8 ak2 = (fg < 2) ? ak : z8;           // [kh|0]
                f32x4 s = __builtin_amdgcn_mfma_f32_16x16x32_bf16(ak2, bq2, zc, 0, 0, 0);
                s = __builtin_amdgcn_mfma_f32_16x16x32_bf16(ak, bq1, s, 0, 0, 0);

                float s2[4];
                if (kt == qt) {
                    const int qr = 16 * wid + fr;
                    const int kc = nrow * 16 + fg * 4;
#pragma unroll
                    for (int reg = 0; reg < 4; ++reg) {
                        float x = s[reg];
                        float y = x * x;
                        s2[reg] = (kc + reg <= qr) ? y : 0.f;
                        zlane += s2[reg];
                    }
                } else {
#pragma unroll
                    for (int reg = 0; reg < 4; ++reg) {
                        float x = s[reg];
                        s2[reg] = x * x;
                        zlane += s2[reg];
                    }
                }
                bf16x4 pv = {(__bf16)s2[0], (__bf16)s2[1], (__bf16)s2[2], (__bf16)s2[3]};
                *(bf16x4*)&P[16 * wid + fr][nrow * 16 + fg * 4] = pv;
            }

            // phase 2: O strip += P_strip @ V (same-wave P)
            const bf16x8 a0 = *(const bf16x8*)&P[16 * wid + fr][fg * 8];
            const bf16x8 a1 = *(const bf16x8*)&P[16 * wid + fr][32 + fg * 8];
#pragma unroll
            for (int nt = 0; nt < 4; ++nt) {
                const bf16x8 b0 = *(const bf16x8*)&vsl[cur][((fg    ) * 64 + nt * 16 + fr) * 8];
                const bf16x8 b1 = *(const bf16x8*)&vsl[cur][((fg + 4) * 64 + nt * 16 + fr) * 8];
                oacc[nt] = __builtin_amdgcn_mfma_f32_16x16x32_bf16(a0, b0, oacc[nt], 0, 0, 0);
                oacc[nt] = __builtin_amdgcn_mfma_f32_16x16x32_bf16(a1, b1, oacc[nt], 0, 0, 0);
            }

            // prefetch drained + all waves' staging visible before next step
            asm volatile("s_waitcnt vmcnt(0)" ::: "memory");
            __builtin_amdgcn_s_barrier();
            cur ^= 1;
        }

        // z: lane groups share q=16*wid+fr -> butterfly over lane^16, lane^32
        float z = zlane;
        z += __shfl_xor(z, 16);
        z += __shfl_xor(z, 32);
        const float zinv = 1.f / (z + 1e-5f);

        // epilogue: oacc D-layout row = fg*4+reg (q), col = fr (d within nt)
#pragma unroll
        for (int reg = 0; reg < 4; ++reg) {
            const float r = __shfl(zinv, fg * 4 + reg);
            const size_t gro = (size_t)(qbase + 16 * wid + fg * 4 + reg) * 1024;
#pragma unroll
            for (int nt = 0; nt < 4; ++nt)
                obh[gro + nt * 16 + fr] = f2b(oacc[nt][reg] * r);
        }
    }
}

extern "C" void kernel_launch(void* const* d_in, const int* in_sizes, int n_in,
                              void* d_out, int out_size, void* d_ws, size_t ws_size,
                              hipStream_t stream) {
    const float* x     = (const float*)d_in[0];
    const float* Wq    = (const float*)d_in[1];
    const float* Wk    = (const float*)d_in[2];
    const float* Wv    = (const float*)d_in[3];
    const float* Wo    = (const float*)d_in[4];
    const float* gamma = (const float*)d_in[5];
    const float* beta  = (const float*)d_in[6];
    float* out = (float*)d_out;
    (void)in_sizes; (void)n_in; (void)out_size; (void)ws_size;

    char* w = (char*)d_ws;
    float*          qk_raw = (float*)w;                                   // 8 MB @ 0
    unsigned short* vTb    = (unsigned short*)(w + (8u  << 20));          // 8 MB [bh][64][2048]
    unsigned short* ob     = (unsigned short*)(w + (16u << 20));          // 8 MB
    unsigned short* xh     = (unsigned short*)(w + (24u << 20));          // 8 MB (dead after gemms)
    unsigned short* xl     = (unsigned short*)(w + (32u << 20));          // 8 MB (dead after gemm_split)
    unsigned short* qhl_g  = (unsigned short*)(w + (24u << 20));          // 4 MB (overlays dead xh)
    unsigned short* khl_g  = (unsigned short*)(w + (28u << 20));          // 4 MB (overlays dead xh)
    unsigned short* wqkh   = (unsigned short*)(w + (40u << 20));          // 1 MB
    unsigned short* wqkl   = (unsigned short*)(w + (41u << 20));          // 1 MB
    unsigned short* wvb    = (unsigned short*)(w + (42u << 20));          // 2 MB
    unsigned short* wob    = (unsigned short*)(w + (44u << 20));          // 2 MB

    cast_split<<<2048, 256, 0, stream>>>(x,  xh, xl, 4096 * 1024);
    cast_split<<<128,  256, 0, stream>>>(Wq, wqkh, wqkl, 256 * 1024);
    cast_split<<<128,  256, 0, stream>>>(Wk, wqkh + 256 * 1024, wqkl + 256 * 1024, 256 * 1024);
    cast_bf16 <<<512,  256, 0, stream>>>(Wv, wvb, 1024 * 1024);
    cast_bf16 <<<512,  256, 0, stream>>>(Wo, wob, 1024 * 1024);

    // qk projection (split-bf16, ~fp32): [4096][512] f32, BM=64 -> 512 blocks
    gemm_split<<<dim3(64, 8), 256, 0, stream>>>(xh, xl, wqkh, wqkl, qk_raw, 4096, 512, 1024);
    // v projection -> transposed bf16 vT[bh][d][l], BM=64 -> 512 blocks
    gemm_mfma<64, 128, 2><<<dim3(64, 8), 256, 0, stream>>>(xh, wvb, vTb, 4096, 1024, 1024);
    // feature map -> q/k hi|lo bf16 [bh][l][32]
    ln_featuremap<<<512, 256, 0, stream>>>(qk_raw, gamma, beta, qhl_g, khl_g);
    // attention -> bf16 ob (b, l, h*64+d)
    rebased_attn<<<dim3(16, 32), 256, 0, stream>>>(qhl_g, khl_g, vTb, ob);
    // output projection -> f32 out, BM=64 -> 512 blocks
    gemm_mfma<64, 128, 0><<<dim3(64, 8), 256, 0, stream>>>(ob, wob, out, 4096, 1024, 1024);
}